// Round 1
// baseline (328.698 us; speedup 1.0000x reference)
//
#include <hip/hip_runtime.h>

#define Bx 32
#define Nx 512
#define Ex 4
#define Fx 128
#define Gx 64
#define HIDx 256
#define EMBx 128
#define NEDGE 8192

// ---------------- K1: Wh[b,e,n,g] = X[b,n,:] @ Ws[e][:,g]; w1/w2 = Wh . a ----
__global__ __launch_bounds__(256) void k1_wh(const float* __restrict__ X,
                                             const float* __restrict__ Ws,
                                             const float* __restrict__ a,
                                             float* __restrict__ Wh,
                                             float* __restrict__ w1,
                                             float* __restrict__ w2) {
    __shared__ float sWs[Fx * Gx];      // 32KB
    __shared__ float sX[32][Fx];        // 16KB
    __shared__ float sa[2 * Gx];
    int be = blockIdx.x; int b = be >> 2; int e = be & 3;
    int n0 = blockIdx.y * 32;
    int tid = threadIdx.x;
    for (int i = tid; i < Fx * Gx; i += 256) sWs[i] = Ws[e * Fx * Gx + i];
    for (int i = tid; i < 32 * Fx; i += 256) sX[i >> 7][i & 127] = X[(size_t)(b * Nx + n0) * Fx + i];
    if (tid < 2 * Gx) sa[tid] = a[e * 2 * Gx + tid];
    __syncthreads();
    int g = tid & 63;
    int w = tid >> 6;
    float a1 = sa[g], a2 = sa[Gx + g];
    for (int rr = 0; rr < 8; ++rr) {
        int r = w + rr * 4;
        float acc = 0.f;
        #pragma unroll 4
        for (int k = 0; k < Fx; ++k) acc += sX[r][k] * sWs[k * Gx + g];
        Wh[((size_t)(be * Nx + n0 + r)) * Gx + g] = acc;
        float p1 = acc * a1, p2 = acc * a2;
        #pragma unroll
        for (int off = 32; off > 0; off >>= 1) {
            p1 += __shfl_xor(p1, off, 64);
            p2 += __shfl_xor(p2, off, 64);
        }
        if (g == 0) {
            w1[be * Nx + n0 + r] = p1;
            w2[be * Nx + n0 + r] = p2;
        }
    }
}

// ---------------- K2: sparse softmax attention aggregate -> H ---------------
__global__ __launch_bounds__(256) void k2_att(const int* __restrict__ edges,
                                              const float* __restrict__ Wh,
                                              const float* __restrict__ w1g,
                                              const float* __restrict__ w2g,
                                              float* __restrict__ H) {
    __shared__ unsigned int cnt[64 * 128];   // 32KB: 64 rows x 512 byte counters
    __shared__ float sw2[Nx];                // 2KB
    __shared__ float sw1[64];
    __shared__ int   lm[4][512];             // 8KB
    __shared__ float lw[4][512];             // 8KB
    int be = blockIdx.x; int b = be >> 2; int e = be & 3;
    int n0 = blockIdx.y * 64;
    int tid = threadIdx.x;
    for (int i = tid; i < 64 * 128; i += 256) cnt[i] = 0u;
    for (int i = tid; i < Nx; i += 256) sw2[i] = w2g[be * Nx + i];
    if (tid < 64) sw1[tid] = w1g[be * Nx + n0 + tid];
    __syncthreads();
    const int* srcp = edges + (size_t)be * 2 * NEDGE;
    const int* dstp = srcp + NEDGE;
    for (int i = tid; i < NEDGE; i += 256) {
        int s = srcp[i], d = dstp[i];
        unsigned int r = (unsigned int)(s - n0);
        if (r < 64u) atomicAdd(&cnt[r * 128 + (d >> 2)], 1u << ((d & 3) * 8));
    }
    __syncthreads();
    int wave = tid >> 6, lane = tid & 63;
    const float* WhB = Wh + (size_t)be * Nx * Gx;
    for (int r = wave; r < 64; r += 4) {
        float w1v = sw1[r];
        unsigned int cw0 = cnt[r * 128 + lane];
        unsigned int cw1 = cnt[r * 128 + 64 + lane];
        float mx = 0.f; int myK = 0;
        #pragma unroll
        for (int t = 0; t < 2; ++t) {
            unsigned int cw = t ? cw1 : cw0;
            int mbase = (t * 64 + lane) * 4;
            #pragma unroll
            for (int jj = 0; jj < 4; ++jj) {
                int c = (cw >> (jj * 8)) & 255;
                if (c) {
                    float s = (w1v + sw2[mbase + jj]) * (float)c;
                    mx = fmaxf(mx, s);
                    myK++;
                }
            }
        }
        int K = myK;
        #pragma unroll
        for (int off = 32; off > 0; off >>= 1) {
            mx = fmaxf(mx, __shfl_xor(mx, off, 64));
            K += __shfl_xor(K, off, 64);
        }
        // exclusive prefix of per-lane nonzero count
        int x = myK;
        #pragma unroll
        for (int d = 1; d < 64; d <<= 1) {
            int y = __shfl_up(x, d, 64);
            if (lane >= d) x += y;
        }
        int off0 = x - myK;
        int tot = __shfl(x, 63, 64);
        float dsum = 0.f; int idx = off0;
        #pragma unroll
        for (int t = 0; t < 2; ++t) {
            unsigned int cw = t ? cw1 : cw0;
            int mbase = (t * 64 + lane) * 4;
            #pragma unroll
            for (int jj = 0; jj < 4; ++jj) {
                int c = (cw >> (jj * 8)) & 255;
                if (c) {
                    float s = (w1v + sw2[mbase + jj]) * (float)c;
                    float ew = __expf(s - mx);
                    dsum += ew;
                    lm[wave][idx] = mbase + jj;
                    lw[wave][idx] = ew * (float)c;
                    idx++;
                }
            }
        }
        #pragma unroll
        for (int off = 32; off > 0; off >>= 1) dsum += __shfl_xor(dsum, off, 64);
        float inv = 1.f / (dsum + (float)(Nx - K) * __expf(-mx));
        float acc = 0.f;
        for (int j = 0; j < tot; ++j) {
            acc += lw[wave][j] * WhB[lm[wave][j] * Gx + lane];
        }
        H[((size_t)(b * Nx + n0 + r)) * (Ex * Gx) + e * Gx + lane] = acc * inv;
    }
}

// ---------------- K3: h_pre = H @ lin0_w + b; per-block column partials -----
__global__ __launch_bounds__(256) void k3_lin0(const float* __restrict__ H,
                                               const float* __restrict__ lin0_w,
                                               const float* __restrict__ lin0_b,
                                               float* __restrict__ h_pre,
                                               float* __restrict__ partials) {
    __shared__ __align__(16) float sH[32 * 256];   // 32KB
    int row0 = blockIdx.x * 32;
    int tid = threadIdx.x;
    for (int i = tid; i < 32 * 256; i += 256) sH[i] = H[(size_t)row0 * 256 + i];
    __syncthreads();
    int j = tid;
    float acc[32];
    #pragma unroll
    for (int r = 0; r < 32; ++r) acc[r] = 0.f;
    const float4* sH4 = reinterpret_cast<const float4*>(sH);
    for (int k4 = 0; k4 < 64; ++k4) {
        float w0 = lin0_w[(k4 * 4 + 0) * HIDx + j];
        float w1_ = lin0_w[(k4 * 4 + 1) * HIDx + j];
        float w2_ = lin0_w[(k4 * 4 + 2) * HIDx + j];
        float w3 = lin0_w[(k4 * 4 + 3) * HIDx + j];
        #pragma unroll
        for (int r = 0; r < 32; ++r) {
            float4 h4 = sH4[r * 64 + k4];
            acc[r] += h4.x * w0 + h4.y * w1_ + h4.z * w2_ + h4.w * w3;
        }
    }
    float bj = lin0_b[j];
    float ps = 0.f, pq = 0.f;
    #pragma unroll
    for (int r = 0; r < 32; ++r) {
        float v = acc[r] + bj;
        h_pre[(size_t)(row0 + r) * HIDx + j] = v;
        ps += v;
        pq += v * v;
    }
    partials[(size_t)blockIdx.x * 2 * HIDx + j] = ps;
    partials[(size_t)blockIdx.x * 2 * HIDx + HIDx + j] = pq;
}

// ---------------- K3b: finalize BN stats -> scale/bias ----------------------
__global__ void k3b_stats(const float* __restrict__ partials,
                          const float* __restrict__ gamma,
                          const float* __restrict__ beta,
                          float* __restrict__ sb) {
    int j = threadIdx.x;  // 256
    float s = 0.f, q = 0.f;
    for (int blk = 0; blk < 512; ++blk) {
        s += partials[blk * 512 + j];
        q += partials[blk * 512 + 256 + j];
    }
    const float invM = 1.f / 16384.f;
    float mu = s * invM;
    float var = fmaxf(q * invM - mu * mu, 0.f);
    float sc = gamma[j] * rsqrtf(var + 1e-5f);
    sb[j] = sc;
    sb[256 + j] = beta[j] - mu * sc;
}

// ---------------- K4: out = elu(bn(h_pre)) @ lin1_w + b ---------------------
__global__ __launch_bounds__(256) void k4_lin1(const float* __restrict__ h_pre,
                                               const float* __restrict__ sb,
                                               const float* __restrict__ lin1_w,
                                               const float* __restrict__ lin1_b,
                                               float* __restrict__ out) {
    __shared__ __align__(16) float sHn[32 * 256];  // 32KB
    int row0 = blockIdx.x * 32;
    int tid = threadIdx.x;
    for (int i = tid; i < 32 * 256; i += 256) {
        int j = i & 255;
        float v = h_pre[(size_t)row0 * 256 + i];
        v = v * sb[j] + sb[256 + j];
        v = v > 0.f ? v : expm1f(v);
        sHn[i] = v;
    }
    __syncthreads();
    int j = tid & 127;
    int tg = tid >> 7;
    float acc[16];
    #pragma unroll
    for (int r = 0; r < 16; ++r) acc[r] = 0.f;
    const float4* sHn4 = reinterpret_cast<const float4*>(sHn);
    for (int k4 = 0; k4 < 64; ++k4) {
        float w0 = lin1_w[(k4 * 4 + 0) * EMBx + j];
        float w1_ = lin1_w[(k4 * 4 + 1) * EMBx + j];
        float w2_ = lin1_w[(k4 * 4 + 2) * EMBx + j];
        float w3 = lin1_w[(k4 * 4 + 3) * EMBx + j];
        #pragma unroll
        for (int r = 0; r < 16; ++r) {
            float4 h4 = sHn4[(tg * 16 + r) * 64 + k4];
            acc[r] += h4.x * w0 + h4.y * w1_ + h4.z * w2_ + h4.w * w3;
        }
    }
    float bj = lin1_b[j];
    #pragma unroll
    for (int r = 0; r < 16; ++r)
        out[(size_t)(row0 + tg * 16 + r) * EMBx + j] = acc[r] + bj;
}

extern "C" void kernel_launch(void* const* d_in, const int* in_sizes, int n_in,
                              void* d_out, int out_size, void* d_ws, size_t ws_size,
                              hipStream_t stream) {
    const float* X      = (const float*)d_in[0];
    const int*   edges  = (const int*)d_in[1];
    const float* Ws     = (const float*)d_in[2];
    const float* a      = (const float*)d_in[3];
    const float* lin0_w = (const float*)d_in[4];
    const float* lin0_b = (const float*)d_in[5];
    const float* gamma  = (const float*)d_in[6];
    const float* beta   = (const float*)d_in[7];
    const float* lin1_w = (const float*)d_in[8];
    const float* lin1_b = (const float*)d_in[9];
    float* ws = (float*)d_ws;

    float* Wh       = ws;                  // 4,194,304 floats
    float* h_pre    = ws;                  // alias: Wh dead after k2
    float* H        = ws + 4194304;        // 4,194,304 floats
    float* w1       = ws + 8388608;        // 65,536
    float* w2       = ws + 8454144;        // 65,536
    float* partials = ws + 8519680;        // 262,144
    float* sb       = ws + 8781824;        // 512
    float* out      = (float*)d_out;

    k1_wh  <<<dim3(Bx * Ex, Nx / 32), 256, 0, stream>>>(X, Ws, a, Wh, w1, w2);
    k2_att <<<dim3(Bx * Ex, Nx / 64), 256, 0, stream>>>(edges, Wh, w1, w2, H);
    k3_lin0<<<dim3(512), 256, 0, stream>>>(H, lin0_w, lin0_b, h_pre, partials);
    k3b_stats<<<1, 256, 0, stream>>>(partials, gamma, beta, sb);
    k4_lin1<<<dim3(512), 256, 0, stream>>>(h_pre, sb, lin1_w, lin1_b, out);
}

// Round 2
// 274.092 us; speedup vs baseline: 1.1992x; 1.1992x over previous
//
#include <hip/hip_runtime.h>

#define Bx 32
#define Nx 512
#define Ex 4
#define Fx 128
#define Gx 64
#define HIDx 256
#define EMBx 128
#define NEDGE 8192

// ---- K1: Wh[be,n,g] = X[b,n,:] @ Ws[e]; w1/w2 = Wh . a  (64x64 reg-tiled) ----
__global__ __launch_bounds__(256) void k1_wh(const float* __restrict__ X,
                                             const float* __restrict__ Ws,
                                             const float* __restrict__ a,
                                             float* __restrict__ Wh,
                                             float* __restrict__ w1,
                                             float* __restrict__ w2) {
    __shared__ float sXT[Fx][68];     // [k][n], pad 4 -> 34.8KB
    __shared__ float red1[16][68];    // per-gq partials for w1
    __shared__ float red2[16][68];
    int be = blockIdx.x; int b = be >> 2; int e = be & 3;
    int n0 = blockIdx.y * 64;
    int tid = threadIdx.x;
    for (int i = tid; i < 64 * Fx; i += 256) {
        int n = i >> 7, k = i & 127;
        sXT[k][n] = X[(size_t)(b * Nx + n0 + n) * Fx + k];
    }
    __syncthreads();
    const float* We = Ws + e * Fx * Gx;
    int gq = tid & 15, nq = tid >> 4;
    int gg = gq * 4, nn = nq * 4;
    float acc[4][4];
    #pragma unroll
    for (int i = 0; i < 4; ++i)
        #pragma unroll
        for (int j = 0; j < 4; ++j) acc[i][j] = 0.f;
    #pragma unroll 4
    for (int k = 0; k < Fx; ++k) {
        float4 av = *(const float4*)&sXT[k][nn];
        float4 bv = *(const float4*)&We[k * Gx + gg];
        float ai[4] = {av.x, av.y, av.z, av.w};
        float bj[4] = {bv.x, bv.y, bv.z, bv.w};
        #pragma unroll
        for (int i = 0; i < 4; ++i)
            #pragma unroll
            for (int j = 0; j < 4; ++j) acc[i][j] += ai[i] * bj[j];
    }
    float a1[4], a2[4];
    #pragma unroll
    for (int j = 0; j < 4; ++j) {
        a1[j] = a[e * 2 * Gx + gg + j];
        a2[j] = a[e * 2 * Gx + Gx + gg + j];
    }
    #pragma unroll
    for (int i = 0; i < 4; ++i) {
        float4 v = {acc[i][0], acc[i][1], acc[i][2], acc[i][3]};
        *(float4*)&Wh[((size_t)be * Nx + n0 + nn + i) * Gx + gg] = v;
        float p1 = acc[i][0] * a1[0] + acc[i][1] * a1[1] + acc[i][2] * a1[2] + acc[i][3] * a1[3];
        float p2 = acc[i][0] * a2[0] + acc[i][1] * a2[1] + acc[i][2] * a2[2] + acc[i][3] * a2[3];
        red1[gq][nn + i] = p1;
        red2[gq][nn + i] = p2;
    }
    __syncthreads();
    if (tid < 64) {
        float s1 = 0.f, s2 = 0.f;
        #pragma unroll
        for (int t = 0; t < 16; ++t) { s1 += red1[t][tid]; s2 += red2[t][tid]; }
        w1[be * Nx + n0 + tid] = s1;
        w2[be * Nx + n0 + tid] = s2;
    }
}

// ---- K2: sparse softmax attention aggregate -> H (vectorized gather) -------
__global__ __launch_bounds__(256) void k2_att(const int* __restrict__ edges,
                                              const float* __restrict__ Wh,
                                              const float* __restrict__ w1g,
                                              const float* __restrict__ w2g,
                                              float* __restrict__ H) {
    __shared__ unsigned int cnt[64 * 128];   // 32KB
    __shared__ float sw2[Nx];                // 2KB
    __shared__ float sw1[64];
    __shared__ int   lm[4][528];             // 8.25KB
    __shared__ float lw[4][528];             // 8.25KB
    int be = blockIdx.x; int b = be >> 2; int e = be & 3;
    int n0 = blockIdx.y * 64;
    int tid = threadIdx.x;
    for (int i = tid; i < 64 * 128; i += 256) cnt[i] = 0u;
    for (int i = tid; i < Nx; i += 256) sw2[i] = w2g[be * Nx + i];
    if (tid < 64) sw1[tid] = w1g[be * Nx + n0 + tid];
    __syncthreads();
    const int* srcp = edges + (size_t)be * 2 * NEDGE;
    const int* dstp = srcp + NEDGE;
    for (int i = tid; i < NEDGE; i += 256) {
        int s = srcp[i], d = dstp[i];
        unsigned int r = (unsigned int)(s - n0);
        if (r < 64u) atomicAdd(&cnt[r * 128 + (d >> 2)], 1u << ((d & 3) * 8));
    }
    __syncthreads();
    int wave = tid >> 6, lane = tid & 63;
    int grp = lane >> 4, gofs = (lane & 15) * 4;
    const float* WhB = Wh + (size_t)be * Nx * Gx;
    for (int r = wave; r < 64; r += 4) {
        float w1v = sw1[r];
        unsigned int cw0 = cnt[r * 128 + lane];
        unsigned int cw1 = cnt[r * 128 + 64 + lane];
        float mx = 0.f; int myK = 0;
        #pragma unroll
        for (int t = 0; t < 2; ++t) {
            unsigned int cw = t ? cw1 : cw0;
            int mbase = (t * 64 + lane) * 4;
            #pragma unroll
            for (int jj = 0; jj < 4; ++jj) {
                int c = (cw >> (jj * 8)) & 255;
                if (c) {
                    float s = (w1v + sw2[mbase + jj]) * (float)c;
                    mx = fmaxf(mx, s);
                    myK++;
                }
            }
        }
        int K = myK;
        #pragma unroll
        for (int off = 32; off > 0; off >>= 1) {
            mx = fmaxf(mx, __shfl_xor(mx, off, 64));
            K += __shfl_xor(K, off, 64);
        }
        int x = myK;
        #pragma unroll
        for (int d = 1; d < 64; d <<= 1) {
            int y = __shfl_up(x, d, 64);
            if (lane >= d) x += y;
        }
        int off0 = x - myK;
        int tot = __shfl(x, 63, 64);
        float dsum = 0.f; int idx = off0;
        #pragma unroll
        for (int t = 0; t < 2; ++t) {
            unsigned int cw = t ? cw1 : cw0;
            int mbase = (t * 64 + lane) * 4;
            #pragma unroll
            for (int jj = 0; jj < 4; ++jj) {
                int c = (cw >> (jj * 8)) & 255;
                if (c) {
                    float s = (w1v + sw2[mbase + jj]) * (float)c;
                    float ew = __expf(s - mx);
                    dsum += ew;
                    lm[wave][idx] = mbase + jj;
                    lw[wave][idx] = ew * (float)c;
                    idx++;
                }
            }
        }
        #pragma unroll
        for (int off = 32; off > 0; off >>= 1) dsum += __shfl_xor(dsum, off, 64);
        float inv = 1.f / (dsum + (float)(Nx - K) * __expf(-mx));
        if (lane < 8) { lm[wave][tot + lane] = 0; lw[wave][tot + lane] = 0.f; }
        float ax = 0.f, ay = 0.f, az = 0.f, aw = 0.f;
        for (int j = 0; j < tot; j += 8) {
            int   m0 = lm[wave][j + grp];
            int   m1 = lm[wave][j + 4 + grp];
            float u0 = lw[wave][j + grp];
            float u1 = lw[wave][j + 4 + grp];
            float4 v0 = *(const float4*)&WhB[(size_t)m0 * Gx + gofs];
            float4 v1 = *(const float4*)&WhB[(size_t)m1 * Gx + gofs];
            ax += u0 * v0.x + u1 * v1.x;
            ay += u0 * v0.y + u1 * v1.y;
            az += u0 * v0.z + u1 * v1.z;
            aw += u0 * v0.w + u1 * v1.w;
        }
        ax += __shfl_xor(ax, 16, 64); ax += __shfl_xor(ax, 32, 64);
        ay += __shfl_xor(ay, 16, 64); ay += __shfl_xor(ay, 32, 64);
        az += __shfl_xor(az, 16, 64); az += __shfl_xor(az, 32, 64);
        aw += __shfl_xor(aw, 16, 64); aw += __shfl_xor(aw, 32, 64);
        if (grp == 0) {
            float4 o = {ax * inv, ay * inv, az * inv, aw * inv};
            *(float4*)&H[((size_t)(b * Nx + n0 + r)) * (Ex * Gx) + e * Gx + gofs] = o;
        }
    }
}

// ---- K3: h_pre = H @ lin0_w + b; per-block column partials -----------------
__global__ __launch_bounds__(256) void k3_lin0(const float* __restrict__ H,
                                               const float* __restrict__ lin0_w,
                                               const float* __restrict__ lin0_b,
                                               float* __restrict__ h_pre,
                                               float* __restrict__ partials) {
    __shared__ __align__(16) float sH[32 * 256];   // 32KB
    int row0 = blockIdx.x * 32;
    int tid = threadIdx.x;
    for (int i = tid; i < 32 * 256; i += 256) sH[i] = H[(size_t)row0 * 256 + i];
    __syncthreads();
    int j = tid;
    float acc[32];
    #pragma unroll
    for (int r = 0; r < 32; ++r) acc[r] = 0.f;
    const float4* sH4 = reinterpret_cast<const float4*>(sH);
    for (int k4 = 0; k4 < 64; ++k4) {
        float w0 = lin0_w[(k4 * 4 + 0) * HIDx + j];
        float w1_ = lin0_w[(k4 * 4 + 1) * HIDx + j];
        float w2_ = lin0_w[(k4 * 4 + 2) * HIDx + j];
        float w3 = lin0_w[(k4 * 4 + 3) * HIDx + j];
        #pragma unroll
        for (int r = 0; r < 32; ++r) {
            float4 h4 = sH4[r * 64 + k4];
            acc[r] += h4.x * w0 + h4.y * w1_ + h4.z * w2_ + h4.w * w3;
        }
    }
    float bj = lin0_b[j];
    float ps = 0.f, pq = 0.f;
    #pragma unroll
    for (int r = 0; r < 32; ++r) {
        float v = acc[r] + bj;
        h_pre[(size_t)(row0 + r) * HIDx + j] = v;
        ps += v;
        pq += v * v;
    }
    partials[(size_t)blockIdx.x * 2 * HIDx + j] = ps;
    partials[(size_t)blockIdx.x * 2 * HIDx + HIDx + j] = pq;
}

// ---- K3b: finalize BN stats -> scale/bias (8 blocks x 8 slices) ------------
__global__ __launch_bounds__(256) void k3b_stats(const float* __restrict__ partials,
                                                 const float* __restrict__ gamma,
                                                 const float* __restrict__ beta,
                                                 float* __restrict__ sb) {
    __shared__ float rs[8][32], rq[8][32];
    int jl = threadIdx.x & 31, sl = threadIdx.x >> 5;
    int j = blockIdx.x * 32 + jl;
    float s = 0.f, q = 0.f;
    for (int blk = sl; blk < 512; blk += 8) {
        s += partials[blk * 512 + j];
        q += partials[blk * 512 + 256 + j];
    }
    rs[sl][jl] = s; rq[sl][jl] = q;
    __syncthreads();
    if (threadIdx.x < 32) {
        float S = 0.f, Q = 0.f;
        #pragma unroll
        for (int t = 0; t < 8; ++t) { S += rs[t][jl]; Q += rq[t][jl]; }
        const float invM = 1.f / 16384.f;
        float mu = S * invM;
        float var = fmaxf(Q * invM - mu * mu, 0.f);
        float sc = gamma[j] * rsqrtf(var + 1e-5f);
        sb[j] = sc;
        sb[256 + j] = beta[j] - mu * sc;
    }
}

// ---- K4: out = elu(bn(h_pre)) @ lin1_w + b ---------------------------------
__global__ __launch_bounds__(256) void k4_lin1(const float* __restrict__ h_pre,
                                               const float* __restrict__ sb,
                                               const float* __restrict__ lin1_w,
                                               const float* __restrict__ lin1_b,
                                               float* __restrict__ out) {
    __shared__ __align__(16) float sHn[32 * 256];  // 32KB
    int row0 = blockIdx.x * 32;
    int tid = threadIdx.x;
    for (int i = tid; i < 32 * 256; i += 256) {
        int j = i & 255;
        float v = h_pre[(size_t)row0 * 256 + i];
        v = v * sb[j] + sb[256 + j];
        v = v > 0.f ? v : expm1f(v);
        sHn[i] = v;
    }
    __syncthreads();
    int j = tid & 127;
    int tg = tid >> 7;
    float acc[16];
    #pragma unroll
    for (int r = 0; r < 16; ++r) acc[r] = 0.f;
    const float4* sHn4 = reinterpret_cast<const float4*>(sHn);
    for (int k4 = 0; k4 < 64; ++k4) {
        float w0 = lin1_w[(k4 * 4 + 0) * EMBx + j];
        float w1_ = lin1_w[(k4 * 4 + 1) * EMBx + j];
        float w2_ = lin1_w[(k4 * 4 + 2) * EMBx + j];
        float w3 = lin1_w[(k4 * 4 + 3) * EMBx + j];
        #pragma unroll
        for (int r = 0; r < 16; ++r) {
            float4 h4 = sHn4[(tg * 16 + r) * 64 + k4];
            acc[r] += h4.x * w0 + h4.y * w1_ + h4.z * w2_ + h4.w * w3;
        }
    }
    float bj = lin1_b[j];
    #pragma unroll
    for (int r = 0; r < 16; ++r)
        out[(size_t)(row0 + tg * 16 + r) * EMBx + j] = acc[r] + bj;
}

extern "C" void kernel_launch(void* const* d_in, const int* in_sizes, int n_in,
                              void* d_out, int out_size, void* d_ws, size_t ws_size,
                              hipStream_t stream) {
    const float* X      = (const float*)d_in[0];
    const int*   edges  = (const int*)d_in[1];
    const float* Ws     = (const float*)d_in[2];
    const float* a      = (const float*)d_in[3];
    const float* lin0_w = (const float*)d_in[4];
    const float* lin0_b = (const float*)d_in[5];
    const float* gamma  = (const float*)d_in[6];
    const float* beta   = (const float*)d_in[7];
    const float* lin1_w = (const float*)d_in[8];
    const float* lin1_b = (const float*)d_in[9];
    float* ws = (float*)d_ws;

    float* Wh       = ws;                  // 4,194,304 floats
    float* h_pre    = ws;                  // alias: Wh dead after k2
    float* H        = ws + 4194304;        // 4,194,304 floats
    float* w1       = ws + 8388608;        // 65,536
    float* w2       = ws + 8454144;        // 65,536
    float* partials = ws + 8519680;        // 262,144
    float* sb       = ws + 8781824;        // 512
    float* out      = (float*)d_out;

    k1_wh  <<<dim3(Bx * Ex, Nx / 64), 256, 0, stream>>>(X, Ws, a, Wh, w1, w2);
    k2_att <<<dim3(Bx * Ex, Nx / 64), 256, 0, stream>>>(edges, Wh, w1, w2, H);
    k3_lin0<<<dim3(512), 256, 0, stream>>>(H, lin0_w, lin0_b, h_pre, partials);
    k3b_stats<<<8, 256, 0, stream>>>(partials, gamma, beta, sb);
    k4_lin1<<<dim3(512), 256, 0, stream>>>(h_pre, sb, lin1_w, lin1_b, out);
}

// Round 3
// 231.508 us; speedup vs baseline: 1.4198x; 1.1839x over previous
//
#include <hip/hip_runtime.h>

#define Bx 32
#define Nx 512
#define Ex 4
#define Fx 128
#define Gx 64
#define HIDx 256
#define EMBx 128
#define NEDGE 8192

typedef __attribute__((ext_vector_type(8))) short bf16x8;
typedef __attribute__((ext_vector_type(4))) float f32x4;

__device__ __forceinline__ ushort f2bf(float x) {
    unsigned int u = __float_as_uint(x);
    u += 0x7fffu + ((u >> 16) & 1u);
    return (ushort)(u >> 16);
}

// ---- K1: Whb[be,g,m] = bf16(X[b,m,:] @ Ws[e][:,g]); w1/w2 = Wh . a ---------
__global__ __launch_bounds__(256) void k1_wh(const float* __restrict__ X,
                                             const float* __restrict__ Ws,
                                             const float* __restrict__ a,
                                             ushort* __restrict__ Whb,
                                             float* __restrict__ w1,
                                             float* __restrict__ w2) {
    __shared__ float sXT[Fx][68];     // [k][n], pad 4
    __shared__ float red1[16][68];
    __shared__ float red2[16][68];
    int be = blockIdx.x; int b = be >> 2; int e = be & 3;
    int n0 = blockIdx.y * 64;
    int tid = threadIdx.x;
    for (int i = tid; i < 64 * Fx; i += 256) {
        int n = i >> 7, k = i & 127;
        sXT[k][n] = X[(size_t)(b * Nx + n0 + n) * Fx + k];
    }
    __syncthreads();
    const float* We = Ws + e * Fx * Gx;
    int gq = tid & 15, nq = tid >> 4;
    int gg = gq * 4, nn = nq * 4;
    float acc[4][4];
    #pragma unroll
    for (int i = 0; i < 4; ++i)
        #pragma unroll
        for (int j = 0; j < 4; ++j) acc[i][j] = 0.f;
    #pragma unroll 4
    for (int k = 0; k < Fx; ++k) {
        float4 av = *(const float4*)&sXT[k][nn];
        float4 bv = *(const float4*)&We[k * Gx + gg];
        float ai[4] = {av.x, av.y, av.z, av.w};
        float bj[4] = {bv.x, bv.y, bv.z, bv.w};
        #pragma unroll
        for (int i = 0; i < 4; ++i)
            #pragma unroll
            for (int j = 0; j < 4; ++j) acc[i][j] += ai[i] * bj[j];
    }
    float a1[4], a2[4];
    #pragma unroll
    for (int j = 0; j < 4; ++j) {
        a1[j] = a[e * 2 * Gx + gg + j];
        a2[j] = a[e * 2 * Gx + Gx + gg + j];
    }
    // transposed bf16 store: Whb[be][g][m]
    #pragma unroll
    for (int j = 0; j < 4; ++j) {
        ushort4 v;
        v.x = f2bf(acc[0][j]); v.y = f2bf(acc[1][j]);
        v.z = f2bf(acc[2][j]); v.w = f2bf(acc[3][j]);
        *(ushort4*)&Whb[((size_t)be * Gx + gg + j) * Nx + n0 + nn] = v;
    }
    #pragma unroll
    for (int i = 0; i < 4; ++i) {
        float p1 = acc[i][0] * a1[0] + acc[i][1] * a1[1] + acc[i][2] * a1[2] + acc[i][3] * a1[3];
        float p2 = acc[i][0] * a2[0] + acc[i][1] * a2[1] + acc[i][2] * a2[2] + acc[i][3] * a2[3];
        red1[gq][nn + i] = p1;
        red2[gq][nn + i] = p2;
    }
    __syncthreads();
    if (tid < 64) {
        float s1 = 0.f, s2 = 0.f;
        #pragma unroll
        for (int t = 0; t < 16; ++t) { s1 += red1[t][tid]; s2 += red2[t][tid]; }
        w1[be * Nx + n0 + tid] = s1;
        w2[be * Nx + n0 + tid] = s2;
    }
}

// ---- K2: counts -> dense bf16 P tile -> MFMA PV -> H -----------------------
__global__ __launch_bounds__(256) void k2_att(const int* __restrict__ edges,
                                              const ushort* __restrict__ Whb,
                                              const float* __restrict__ w1g,
                                              const float* __restrict__ w2g,
                                              float* __restrict__ H) {
    __shared__ unsigned int cnt[32 * 128];   // 16KB byte counters
    __shared__ float sw2[Nx];                // 2KB
    __shared__ float sw1[32];
    __shared__ float sinv[32];
    __shared__ ushort P[32 * 512];           // 32KB bf16, XOR-swizzled rows
    int be = blockIdx.y; int b = be >> 2; int e = be & 3;
    int n0 = blockIdx.x * 32;
    int tid = threadIdx.x;
    for (int i = tid; i < 32 * 128; i += 256) cnt[i] = 0u;
    for (int i = tid; i < Nx; i += 256) sw2[i] = w2g[be * Nx + i];
    if (tid < 32) sw1[tid] = w1g[be * Nx + n0 + tid];
    __syncthreads();
    const int4* srcp = (const int4*)(edges + (size_t)be * 2 * NEDGE);
    const int4* dstp = (const int4*)(edges + (size_t)be * 2 * NEDGE + NEDGE);
    for (int i = tid; i < NEDGE / 4; i += 256) {
        int4 s4 = srcp[i]; int4 d4 = dstp[i];
        int ss[4] = {s4.x, s4.y, s4.z, s4.w};
        int dd[4] = {d4.x, d4.y, d4.z, d4.w};
        #pragma unroll
        for (int u = 0; u < 4; ++u) {
            unsigned int r = (unsigned int)(ss[u] - n0);
            if (r < 32u) atomicAdd(&cnt[r * 128 + (dd[u] >> 2)], 1u << ((dd[u] & 3) * 8));
        }
    }
    __syncthreads();
    int wave = tid >> 6, lane = tid & 63;
    // ---- phase 3: per-row softmax weights, dense write into P --------------
    for (int r = wave; r < 32; r += 4) {
        float w1v = sw1[r];
        unsigned int cw0 = cnt[r * 128 + lane];
        unsigned int cw1 = cnt[r * 128 + 64 + lane];
        float4 s2a = *(const float4*)&sw2[lane * 4];
        float4 s2b = *(const float4*)&sw2[256 + lane * 4];
        int cc[8];
        cc[0] = cw0 & 255; cc[1] = (cw0 >> 8) & 255; cc[2] = (cw0 >> 16) & 255; cc[3] = (cw0 >> 24) & 255;
        cc[4] = cw1 & 255; cc[5] = (cw1 >> 8) & 255; cc[6] = (cw1 >> 16) & 255; cc[7] = (cw1 >> 24) & 255;
        float sc[8];
        sc[0] = (w1v + s2a.x) * (float)cc[0];
        sc[1] = (w1v + s2a.y) * (float)cc[1];
        sc[2] = (w1v + s2a.z) * (float)cc[2];
        sc[3] = (w1v + s2a.w) * (float)cc[3];
        sc[4] = (w1v + s2b.x) * (float)cc[4];
        sc[5] = (w1v + s2b.y) * (float)cc[5];
        sc[6] = (w1v + s2b.z) * (float)cc[6];
        sc[7] = (w1v + s2b.w) * (float)cc[7];
        float mx = 0.f; int K = 0;
        #pragma unroll
        for (int u = 0; u < 8; ++u) {
            if (cc[u]) { mx = fmaxf(mx, sc[u]); K++; }
        }
        #pragma unroll
        for (int off = 32; off > 0; off >>= 1) {
            mx = fmaxf(mx, __shfl_xor(mx, off, 64));
            K += __shfl_xor(K, off, 64);
        }
        float dsum = 0.f;
        ushort pv[8];
        #pragma unroll
        for (int u = 0; u < 8; ++u) {
            if (cc[u]) {
                float ew = __expf(sc[u] - mx);
                dsum += ew;
                pv[u] = f2bf(ew * (float)cc[u]);
            } else pv[u] = 0;
        }
        #pragma unroll
        for (int off = 32; off > 0; off >>= 1) dsum += __shfl_xor(dsum, off, 64);
        if (lane == 0) sinv[r] = 1.f / (dsum + (float)(Nx - K) * __expf(-mx));
        unsigned int swz = (unsigned int)((r & 7) << 4);
        uint2 wlo, whi;
        wlo.x = (unsigned int)pv[0] | ((unsigned int)pv[1] << 16);
        wlo.y = (unsigned int)pv[2] | ((unsigned int)pv[3] << 16);
        whi.x = (unsigned int)pv[4] | ((unsigned int)pv[5] << 16);
        whi.y = (unsigned int)pv[6] | ((unsigned int)pv[7] << 16);
        *(uint2*)((char*)P + (((unsigned)(r * 1024 + lane * 8)) ^ swz)) = wlo;
        *(uint2*)((char*)P + (((unsigned)(r * 1024 + 512 + lane * 8)) ^ swz)) = whi;
    }
    __syncthreads();
    // ---- phase 4: H-tile = P @ Whb (MFMA), scale by sinv --------------------
    int r0 = (wave >> 1) * 16;          // waves 0,1: rows 0-15; 2,3: rows 16-31
    int c0 = (wave & 1) * 32;           // waves 0,2: cols 0-31; 1,3: 32-63
    int row = r0 + (lane & 15);
    int kgrp = lane >> 4;
    f32x4 acc0 = {0.f, 0.f, 0.f, 0.f};
    f32x4 acc1 = {0.f, 0.f, 0.f, 0.f};
    const ushort* WB = Whb + (size_t)be * Gx * Nx;
    int g0 = c0 + (lane & 15);
    const ushort* B0 = WB + (size_t)g0 * Nx + kgrp * 8;
    const ushort* B1 = WB + (size_t)(g0 + 16) * Nx + kgrp * 8;
    unsigned int aswz = (unsigned int)((row & 7) << 4);
    #pragma unroll
    for (int ks = 0; ks < 16; ++ks) {
        unsigned int abyte = ((unsigned)(row * 1024 + ks * 64 + kgrp * 16)) ^ aswz;
        bf16x8 af = *(const bf16x8*)((const char*)P + abyte);
        bf16x8 bf0 = *(const bf16x8*)(B0 + ks * 32);
        bf16x8 bf1 = *(const bf16x8*)(B1 + ks * 32);
        acc0 = __builtin_amdgcn_mfma_f32_16x16x32_bf16(af, bf0, acc0, 0, 0, 0);
        acc1 = __builtin_amdgcn_mfma_f32_16x16x32_bf16(af, bf1, acc1, 0, 0, 0);
    }
    float4 iv = *(const float4*)&sinv[r0 + kgrp * 4];
    float ivv[4] = {iv.x, iv.y, iv.z, iv.w};
    #pragma unroll
    for (int reg = 0; reg < 4; ++reg) {
        int rr = n0 + r0 + kgrp * 4 + reg;
        float* Hp = &H[((size_t)(b * Nx) + rr) * (Ex * Gx) + e * Gx + c0 + (lane & 15)];
        Hp[0]  = acc0[reg] * ivv[reg];
        Hp[16] = acc1[reg] * ivv[reg];
    }
}

// ---- K3: h_pre = H @ lin0_w + b; per-block column partials -----------------
__global__ __launch_bounds__(256) void k3_lin0(const float* __restrict__ H,
                                               const float* __restrict__ lin0_w,
                                               const float* __restrict__ lin0_b,
                                               float* __restrict__ h_pre,
                                               float* __restrict__ partials) {
    __shared__ __align__(16) float sH[32 * 256];   // 32KB
    int row0 = blockIdx.x * 32;
    int tid = threadIdx.x;
    for (int i = tid; i < 32 * 256; i += 256) sH[i] = H[(size_t)row0 * 256 + i];
    __syncthreads();
    int j = tid;
    float acc[32];
    #pragma unroll
    for (int r = 0; r < 32; ++r) acc[r] = 0.f;
    const float4* sH4 = reinterpret_cast<const float4*>(sH);
    for (int k4 = 0; k4 < 64; ++k4) {
        float w0 = lin0_w[(k4 * 4 + 0) * HIDx + j];
        float w1_ = lin0_w[(k4 * 4 + 1) * HIDx + j];
        float w2_ = lin0_w[(k4 * 4 + 2) * HIDx + j];
        float w3 = lin0_w[(k4 * 4 + 3) * HIDx + j];
        #pragma unroll
        for (int r = 0; r < 32; ++r) {
            float4 h4 = sH4[r * 64 + k4];
            acc[r] += h4.x * w0 + h4.y * w1_ + h4.z * w2_ + h4.w * w3;
        }
    }
    float bj = lin0_b[j];
    float ps = 0.f, pq = 0.f;
    #pragma unroll
    for (int r = 0; r < 32; ++r) {
        float v = acc[r] + bj;
        h_pre[(size_t)(row0 + r) * HIDx + j] = v;
        ps += v;
        pq += v * v;
    }
    partials[(size_t)blockIdx.x * 2 * HIDx + j] = ps;
    partials[(size_t)blockIdx.x * 2 * HIDx + HIDx + j] = pq;
}

// ---- K3b: finalize BN stats -> scale/bias (8 blocks x 8 slices) ------------
__global__ __launch_bounds__(256) void k3b_stats(const float* __restrict__ partials,
                                                 const float* __restrict__ gamma,
                                                 const float* __restrict__ beta,
                                                 float* __restrict__ sb) {
    __shared__ float rs[8][32], rq[8][32];
    int jl = threadIdx.x & 31, sl = threadIdx.x >> 5;
    int j = blockIdx.x * 32 + jl;
    float s = 0.f, q = 0.f;
    for (int blk = sl; blk < 512; blk += 8) {
        s += partials[blk * 512 + j];
        q += partials[blk * 512 + 256 + j];
    }
    rs[sl][jl] = s; rq[sl][jl] = q;
    __syncthreads();
    if (threadIdx.x < 32) {
        float S = 0.f, Q = 0.f;
        #pragma unroll
        for (int t = 0; t < 8; ++t) { S += rs[t][jl]; Q += rq[t][jl]; }
        const float invM = 1.f / 16384.f;
        float mu = S * invM;
        float var = fmaxf(Q * invM - mu * mu, 0.f);
        float sc = gamma[j] * rsqrtf(var + 1e-5f);
        sb[j] = sc;
        sb[256 + j] = beta[j] - mu * sc;
    }
}

// ---- K4: out = elu(bn(h_pre)) @ lin1_w + b ---------------------------------
__global__ __launch_bounds__(256) void k4_lin1(const float* __restrict__ h_pre,
                                               const float* __restrict__ sb,
                                               const float* __restrict__ lin1_w,
                                               const float* __restrict__ lin1_b,
                                               float* __restrict__ out) {
    __shared__ __align__(16) float sHn[32 * 256];  // 32KB
    int row0 = blockIdx.x * 32;
    int tid = threadIdx.x;
    for (int i = tid; i < 32 * 256; i += 256) {
        int j = i & 255;
        float v = h_pre[(size_t)row0 * 256 + i];
        v = v * sb[j] + sb[256 + j];
        v = v > 0.f ? v : expm1f(v);
        sHn[i] = v;
    }
    __syncthreads();
    int j = tid & 127;
    int tg = tid >> 7;
    float acc[16];
    #pragma unroll
    for (int r = 0; r < 16; ++r) acc[r] = 0.f;
    const float4* sHn4 = reinterpret_cast<const float4*>(sHn);
    for (int k4 = 0; k4 < 64; ++k4) {
        float w0 = lin1_w[(k4 * 4 + 0) * EMBx + j];
        float w1_ = lin1_w[(k4 * 4 + 1) * EMBx + j];
        float w2_ = lin1_w[(k4 * 4 + 2) * EMBx + j];
        float w3 = lin1_w[(k4 * 4 + 3) * EMBx + j];
        #pragma unroll
        for (int r = 0; r < 16; ++r) {
            float4 h4 = sHn4[(tg * 16 + r) * 64 + k4];
            acc[r] += h4.x * w0 + h4.y * w1_ + h4.z * w2_ + h4.w * w3;
        }
    }
    float bj = lin1_b[j];
    #pragma unroll
    for (int r = 0; r < 16; ++r)
        out[(size_t)(row0 + tg * 16 + r) * EMBx + j] = acc[r] + bj;
}

extern "C" void kernel_launch(void* const* d_in, const int* in_sizes, int n_in,
                              void* d_out, int out_size, void* d_ws, size_t ws_size,
                              hipStream_t stream) {
    const float* X      = (const float*)d_in[0];
    const int*   edges  = (const int*)d_in[1];
    const float* Ws     = (const float*)d_in[2];
    const float* a      = (const float*)d_in[3];
    const float* lin0_w = (const float*)d_in[4];
    const float* lin0_b = (const float*)d_in[5];
    const float* gamma  = (const float*)d_in[6];
    const float* beta   = (const float*)d_in[7];
    const float* lin1_w = (const float*)d_in[8];
    const float* lin1_b = (const float*)d_in[9];
    float* ws = (float*)d_ws;

    // region0 (4,194,304 floats): Whb (bf16, 2,097,152 floats worth) during
    // k1/k2; h_pre (fp32) during k3/k4 — Whb dead before h_pre written.
    ushort* Whb     = (ushort*)ws;
    float*  h_pre   = ws;
    float*  H       = ws + 4194304;
    float*  w1      = ws + 8388608;
    float*  w2      = ws + 8454144;
    float*  partials= ws + 8519680;
    float*  sb      = ws + 8781824;
    float*  out     = (float*)d_out;

    k1_wh  <<<dim3(Bx * Ex, Nx / 64), 256, 0, stream>>>(X, Ws, a, Whb, w1, w2);
    k2_att <<<dim3(Nx / 32, Bx * Ex), 256, 0, stream>>>(edges, Whb, w1, w2, H);
    k3_lin0<<<dim3(512), 256, 0, stream>>>(H, lin0_w, lin0_b, h_pre, partials);
    k3b_stats<<<8, 256, 0, stream>>>(partials, gamma, beta, sb);
    k4_lin1<<<dim3(512), 256, 0, stream>>>(h_pre, sb, lin1_w, lin1_b, out);
}

// Round 4
// 166.527 us; speedup vs baseline: 1.9738x; 1.3902x over previous
//
#include <hip/hip_runtime.h>

#define Bx 32
#define Nx 512
#define Ex 4
#define Fx 128
#define Gx 64
#define HIDx 256
#define EMBx 128
#define NEDGE 8192

typedef __attribute__((ext_vector_type(8))) short bf16x8;
typedef __attribute__((ext_vector_type(4))) float f32x4;

__device__ __forceinline__ ushort f2bf(float x) {
    unsigned int u = __float_as_uint(x);
    u += 0x7fffu + ((u >> 16) & 1u);
    return (ushort)(u >> 16);
}
__device__ __forceinline__ float bf2f(ushort h) {
    return __uint_as_float(((unsigned int)h) << 16);
}

// ---- K0: W0T[j][k] = bf16(lin0_w[k][j]); W1T[j][k] = bf16(lin1_w[k][j]) ----
__global__ __launch_bounds__(256) void k0_convert(const float* __restrict__ w0,
                                                  const float* __restrict__ w1,
                                                  ushort* __restrict__ W0T,
                                                  ushort* __restrict__ W1T) {
    int j = blockIdx.x, k = threadIdx.x;
    if (j < HIDx) {
        W0T[j * HIDx + k] = f2bf(w0[k * HIDx + j]);
    } else {
        int jj = j - HIDx;
        W1T[jj * HIDx + k] = f2bf(w1[k * EMBx + jj]);
    }
}

// ---- K1: Whb[be,g,m] = bf16(X[b,m,:] @ Ws[e][:,g]); w1/w2 = Wh . a ---------
__global__ __launch_bounds__(256) void k1_wh(const float* __restrict__ X,
                                             const float* __restrict__ Ws,
                                             const float* __restrict__ a,
                                             ushort* __restrict__ Whb,
                                             float* __restrict__ w1,
                                             float* __restrict__ w2) {
    __shared__ float sXT[Fx][68];
    __shared__ float red1[16][68];
    __shared__ float red2[16][68];
    int be = blockIdx.x; int b = be >> 2; int e = be & 3;
    int n0 = blockIdx.y * 64;
    int tid = threadIdx.x;
    for (int i = tid; i < 64 * Fx; i += 256) {
        int n = i >> 7, k = i & 127;
        sXT[k][n] = X[(size_t)(b * Nx + n0 + n) * Fx + k];
    }
    __syncthreads();
    const float* We = Ws + e * Fx * Gx;
    int gq = tid & 15, nq = tid >> 4;
    int gg = gq * 4, nn = nq * 4;
    float acc[4][4];
    #pragma unroll
    for (int i = 0; i < 4; ++i)
        #pragma unroll
        for (int j = 0; j < 4; ++j) acc[i][j] = 0.f;
    #pragma unroll 4
    for (int k = 0; k < Fx; ++k) {
        float4 av = *(const float4*)&sXT[k][nn];
        float4 bv = *(const float4*)&We[k * Gx + gg];
        float ai[4] = {av.x, av.y, av.z, av.w};
        float bj[4] = {bv.x, bv.y, bv.z, bv.w};
        #pragma unroll
        for (int i = 0; i < 4; ++i)
            #pragma unroll
            for (int j = 0; j < 4; ++j) acc[i][j] += ai[i] * bj[j];
    }
    float a1[4], a2[4];
    #pragma unroll
    for (int j = 0; j < 4; ++j) {
        a1[j] = a[e * 2 * Gx + gg + j];
        a2[j] = a[e * 2 * Gx + Gx + gg + j];
    }
    #pragma unroll
    for (int j = 0; j < 4; ++j) {
        ushort4 v;
        v.x = f2bf(acc[0][j]); v.y = f2bf(acc[1][j]);
        v.z = f2bf(acc[2][j]); v.w = f2bf(acc[3][j]);
        *(ushort4*)&Whb[((size_t)be * Gx + gg + j) * Nx + n0 + nn] = v;
    }
    #pragma unroll
    for (int i = 0; i < 4; ++i) {
        float p1 = acc[i][0] * a1[0] + acc[i][1] * a1[1] + acc[i][2] * a1[2] + acc[i][3] * a1[3];
        float p2 = acc[i][0] * a2[0] + acc[i][1] * a2[1] + acc[i][2] * a2[2] + acc[i][3] * a2[3];
        red1[gq][nn + i] = p1;
        red2[gq][nn + i] = p2;
    }
    __syncthreads();
    if (tid < 64) {
        float s1 = 0.f, s2 = 0.f;
        #pragma unroll
        for (int t = 0; t < 16; ++t) { s1 += red1[t][tid]; s2 += red2[t][tid]; }
        w1[be * Nx + tid + n0] = s1;
        w2[be * Nx + tid + n0] = s2;
    }
}

// ---- K2: counts -> dense bf16 P tile -> MFMA PV -> Hb (bf16) ---------------
__global__ __launch_bounds__(256) void k2_att(const int* __restrict__ edges,
                                              const ushort* __restrict__ Whb,
                                              const float* __restrict__ w1g,
                                              const float* __restrict__ w2g,
                                              ushort* __restrict__ Hb) {
    __shared__ unsigned int cnt[32 * 128];
    __shared__ float sw2[Nx];
    __shared__ float sw1[32];
    __shared__ float sinv[32];
    __shared__ ushort P[32 * 512];
    int be = blockIdx.y; int b = be >> 2; int e = be & 3;
    int n0 = blockIdx.x * 32;
    int tid = threadIdx.x;
    for (int i = tid; i < 32 * 128; i += 256) cnt[i] = 0u;
    for (int i = tid; i < Nx; i += 256) sw2[i] = w2g[be * Nx + i];
    if (tid < 32) sw1[tid] = w1g[be * Nx + n0 + tid];
    __syncthreads();
    const int4* srcp = (const int4*)(edges + (size_t)be * 2 * NEDGE);
    const int4* dstp = (const int4*)(edges + (size_t)be * 2 * NEDGE + NEDGE);
    for (int i = tid; i < NEDGE / 4; i += 256) {
        int4 s4 = srcp[i]; int4 d4 = dstp[i];
        int ss[4] = {s4.x, s4.y, s4.z, s4.w};
        int dd[4] = {d4.x, d4.y, d4.z, d4.w};
        #pragma unroll
        for (int u = 0; u < 4; ++u) {
            unsigned int r = (unsigned int)(ss[u] - n0);
            if (r < 32u) atomicAdd(&cnt[r * 128 + (dd[u] >> 2)], 1u << ((dd[u] & 3) * 8));
        }
    }
    __syncthreads();
    int wave = tid >> 6, lane = tid & 63;
    for (int r = wave; r < 32; r += 4) {
        float w1v = sw1[r];
        unsigned int cw0 = cnt[r * 128 + lane];
        unsigned int cw1 = cnt[r * 128 + 64 + lane];
        float4 s2a = *(const float4*)&sw2[lane * 4];
        float4 s2b = *(const float4*)&sw2[256 + lane * 4];
        int cc[8];
        cc[0] = cw0 & 255; cc[1] = (cw0 >> 8) & 255; cc[2] = (cw0 >> 16) & 255; cc[3] = (cw0 >> 24) & 255;
        cc[4] = cw1 & 255; cc[5] = (cw1 >> 8) & 255; cc[6] = (cw1 >> 16) & 255; cc[7] = (cw1 >> 24) & 255;
        float sc[8];
        sc[0] = (w1v + s2a.x) * (float)cc[0];
        sc[1] = (w1v + s2a.y) * (float)cc[1];
        sc[2] = (w1v + s2a.z) * (float)cc[2];
        sc[3] = (w1v + s2a.w) * (float)cc[3];
        sc[4] = (w1v + s2b.x) * (float)cc[4];
        sc[5] = (w1v + s2b.y) * (float)cc[5];
        sc[6] = (w1v + s2b.z) * (float)cc[6];
        sc[7] = (w1v + s2b.w) * (float)cc[7];
        float mx = 0.f; int K = 0;
        #pragma unroll
        for (int u = 0; u < 8; ++u) {
            if (cc[u]) { mx = fmaxf(mx, sc[u]); K++; }
        }
        #pragma unroll
        for (int off = 32; off > 0; off >>= 1) {
            mx = fmaxf(mx, __shfl_xor(mx, off, 64));
            K += __shfl_xor(K, off, 64);
        }
        float dsum = 0.f;
        ushort pv[8];
        #pragma unroll
        for (int u = 0; u < 8; ++u) {
            if (cc[u]) {
                float ew = __expf(sc[u] - mx);
                dsum += ew;
                pv[u] = f2bf(ew * (float)cc[u]);
            } else pv[u] = 0;
        }
        #pragma unroll
        for (int off = 32; off > 0; off >>= 1) dsum += __shfl_xor(dsum, off, 64);
        if (lane == 0) sinv[r] = 1.f / (dsum + (float)(Nx - K) * __expf(-mx));
        unsigned int swz = (unsigned int)((r & 7) << 4);
        uint2 wlo, whi;
        wlo.x = (unsigned int)pv[0] | ((unsigned int)pv[1] << 16);
        wlo.y = (unsigned int)pv[2] | ((unsigned int)pv[3] << 16);
        whi.x = (unsigned int)pv[4] | ((unsigned int)pv[5] << 16);
        whi.y = (unsigned int)pv[6] | ((unsigned int)pv[7] << 16);
        *(uint2*)((char*)P + (((unsigned)(r * 1024 + lane * 8)) ^ swz)) = wlo;
        *(uint2*)((char*)P + (((unsigned)(r * 1024 + 512 + lane * 8)) ^ swz)) = whi;
    }
    __syncthreads();
    int r0 = (wave >> 1) * 16;
    int c0 = (wave & 1) * 32;
    int row = r0 + (lane & 15);
    int kgrp = lane >> 4;
    f32x4 acc0 = {0.f, 0.f, 0.f, 0.f};
    f32x4 acc1 = {0.f, 0.f, 0.f, 0.f};
    const ushort* WB = Whb + (size_t)be * Gx * Nx;
    int g0 = c0 + (lane & 15);
    const ushort* B0 = WB + (size_t)g0 * Nx + kgrp * 8;
    const ushort* B1 = WB + (size_t)(g0 + 16) * Nx + kgrp * 8;
    unsigned int aswz = (unsigned int)((row & 7) << 4);
    #pragma unroll
    for (int ks = 0; ks < 16; ++ks) {
        unsigned int abyte = ((unsigned)(row * 1024 + ks * 64 + kgrp * 16)) ^ aswz;
        bf16x8 af = *(const bf16x8*)((const char*)P + abyte);
        bf16x8 bf0 = *(const bf16x8*)(B0 + ks * 32);
        bf16x8 bf1 = *(const bf16x8*)(B1 + ks * 32);
        acc0 = __builtin_amdgcn_mfma_f32_16x16x32_bf16(af, bf0, acc0, 0, 0, 0);
        acc1 = __builtin_amdgcn_mfma_f32_16x16x32_bf16(af, bf1, acc1, 0, 0, 0);
    }
    float4 iv = *(const float4*)&sinv[r0 + kgrp * 4];
    float ivv[4] = {iv.x, iv.y, iv.z, iv.w};
    #pragma unroll
    for (int reg = 0; reg < 4; ++reg) {
        int rr = n0 + r0 + kgrp * 4 + reg;
        ushort* Hp = &Hb[((size_t)(b * Nx) + rr) * (Ex * Gx) + e * Gx + c0 + (lane & 15)];
        Hp[0]  = f2bf(acc0[reg] * ivv[reg]);
        Hp[16] = f2bf(acc1[reg] * ivv[reg]);
    }
}

// ---- K3: h_pre = bf16(Hb @ W0 + b) via MFMA; fp32 BN partials --------------
__global__ __launch_bounds__(256) void k3_lin0(const ushort* __restrict__ Hb,
                                               const ushort* __restrict__ W0T,
                                               const float* __restrict__ lin0_b,
                                               ushort* __restrict__ h_pre,
                                               float* __restrict__ partials) {
    __shared__ float red_s[2][256], red_q[2][256];
    int tid = threadIdx.x, wave = tid >> 6, lane = tid & 63;
    int wr = wave >> 1, wc = wave & 1;
    int row0 = blockIdx.x * 32 + wr * 16;
    int arow = lane & 15, kg = lane >> 4;
    const ushort* A = Hb + (size_t)(row0 + arow) * HIDx;
    f32x4 acc[8];
    #pragma unroll
    for (int t = 0; t < 8; ++t) acc[t] = (f32x4){0.f, 0.f, 0.f, 0.f};
    #pragma unroll
    for (int ks = 0; ks < 8; ++ks) {
        int k0 = ks * 32 + kg * 8;
        bf16x8 af = *(const bf16x8*)&A[k0];
        #pragma unroll
        for (int jt = 0; jt < 8; ++jt) {
            bf16x8 bf = *(const bf16x8*)&W0T[(size_t)(wc * 128 + jt * 16 + arow) * HIDx + k0];
            acc[jt] = __builtin_amdgcn_mfma_f32_16x16x32_bf16(af, bf, acc[jt], 0, 0, 0);
        }
    }
    #pragma unroll
    for (int jt = 0; jt < 8; ++jt) {
        int col = wc * 128 + jt * 16 + arow;
        float b = lin0_b[col];
        float s = 0.f, q = 0.f;
        #pragma unroll
        for (int reg = 0; reg < 4; ++reg) {
            float v = acc[jt][reg] + b;
            h_pre[(size_t)(row0 + kg * 4 + reg) * HIDx + col] = f2bf(v);
            s += v; q += v * v;
        }
        s += __shfl_xor(s, 16, 64); s += __shfl_xor(s, 32, 64);
        q += __shfl_xor(q, 16, 64); q += __shfl_xor(q, 32, 64);
        if (lane < 16) { red_s[wr][col] = s; red_q[wr][col] = q; }
    }
    __syncthreads();
    int j = tid;
    partials[(size_t)blockIdx.x * 2 * HIDx + j] = red_s[0][j] + red_s[1][j];
    partials[(size_t)blockIdx.x * 2 * HIDx + HIDx + j] = red_q[0][j] + red_q[1][j];
}

// ---- K3b: finalize BN stats -> scale/bias ----------------------------------
__global__ __launch_bounds__(256) void k3b_stats(const float* __restrict__ partials,
                                                 const float* __restrict__ gamma,
                                                 const float* __restrict__ beta,
                                                 float* __restrict__ sb) {
    __shared__ float rs[8][32], rq[8][32];
    int jl = threadIdx.x & 31, sl = threadIdx.x >> 5;
    int j = blockIdx.x * 32 + jl;
    float s = 0.f, q = 0.f;
    for (int blk = sl; blk < 512; blk += 8) {
        s += partials[blk * 512 + j];
        q += partials[blk * 512 + 256 + j];
    }
    rs[sl][jl] = s; rq[sl][jl] = q;
    __syncthreads();
    if (threadIdx.x < 32) {
        float S = 0.f, Q = 0.f;
        #pragma unroll
        for (int t = 0; t < 8; ++t) { S += rs[t][jl]; Q += rq[t][jl]; }
        const float invM = 1.f / 16384.f;
        float mu = S * invM;
        float var = fmaxf(Q * invM - mu * mu, 0.f);
        float sc = gamma[j] * rsqrtf(var + 1e-5f);
        sb[j] = sc;
        sb[256 + j] = beta[j] - mu * sc;
    }
}

// ---- K4: out = elu(bn(h_pre)) @ W1 + b via MFMA ----------------------------
__global__ __launch_bounds__(256) void k4_lin1(const ushort* __restrict__ h_pre,
                                               const float* __restrict__ sb,
                                               const ushort* __restrict__ W1T,
                                               const float* __restrict__ lin1_b,
                                               float* __restrict__ out) {
    int tid = threadIdx.x, wave = tid >> 6, lane = tid & 63;
    int wr = wave >> 1, wc = wave & 1;
    int row0 = blockIdx.x * 32 + wr * 16;
    int arow = lane & 15, kg = lane >> 4;
    const ushort* A = h_pre + (size_t)(row0 + arow) * HIDx;
    f32x4 acc[4];
    #pragma unroll
    for (int t = 0; t < 4; ++t) acc[t] = (f32x4){0.f, 0.f, 0.f, 0.f};
    #pragma unroll
    for (int ks = 0; ks < 8; ++ks) {
        int k0 = ks * 32 + kg * 8;
        bf16x8 hv = *(const bf16x8*)&A[k0];
        float4 sc0 = *(const float4*)&sb[k0];
        float4 sc1 = *(const float4*)&sb[k0 + 4];
        float4 bi0 = *(const float4*)&sb[256 + k0];
        float4 bi1 = *(const float4*)&sb[256 + k0 + 4];
        float scv[8] = {sc0.x, sc0.y, sc0.z, sc0.w, sc1.x, sc1.y, sc1.z, sc1.w};
        float biv[8] = {bi0.x, bi0.y, bi0.z, bi0.w, bi1.x, bi1.y, bi1.z, bi1.w};
        bf16x8 af;
        #pragma unroll
        for (int u = 0; u < 8; ++u) {
            float v = bf2f((ushort)hv[u]) * scv[u] + biv[u];
            v = v > 0.f ? v : expm1f(v);
            af[u] = (short)f2bf(v);
        }
        #pragma unroll
        for (int jt = 0; jt < 4; ++jt) {
            bf16x8 bf = *(const bf16x8*)&W1T[(size_t)(wc * 64 + jt * 16 + arow) * HIDx + k0];
            acc[jt] = __builtin_amdgcn_mfma_f32_16x16x32_bf16(af, bf, acc[jt], 0, 0, 0);
        }
    }
    #pragma unroll
    for (int jt = 0; jt < 4; ++jt) {
        int col = wc * 64 + jt * 16 + arow;
        float b = lin1_b[col];
        #pragma unroll
        for (int reg = 0; reg < 4; ++reg)
            out[(size_t)(row0 + kg * 4 + reg) * EMBx + col] = acc[jt][reg] + b;
    }
}

extern "C" void kernel_launch(void* const* d_in, const int* in_sizes, int n_in,
                              void* d_out, int out_size, void* d_ws, size_t ws_size,
                              hipStream_t stream) {
    const float* X      = (const float*)d_in[0];
    const int*   edges  = (const int*)d_in[1];
    const float* Ws     = (const float*)d_in[2];
    const float* a      = (const float*)d_in[3];
    const float* lin0_w = (const float*)d_in[4];
    const float* lin0_b = (const float*)d_in[5];
    const float* gamma  = (const float*)d_in[6];
    const float* beta   = (const float*)d_in[7];
    const float* lin1_w = (const float*)d_in[8];
    const float* lin1_b = (const float*)d_in[9];
    float* ws = (float*)d_ws;

    // region0 (4M floats): Whb bf16 (k1,k2) then h_pre bf16 (k3,k4)
    ushort* Whb     = (ushort*)ws;
    ushort* h_pre   = (ushort*)ws;
    ushort* Hb      = (ushort*)(ws + 4194304);   // bf16 [16384][256]
    float*  w1      = ws + 8388608;              // 65,536 (k1->k2 only)
    float*  w2      = ws + 8454144;              // 65,536 (k1->k2 only)
    ushort* W0T     = (ushort*)(ws + 8388608);   // alias w1/w2: k0 runs after k2
    ushort* W1T     = (ushort*)(ws + 8421376);   // 65536 ushorts after W0T
    float*  partials= ws + 8519680;              // 512*512
    float*  sb      = ws + 8781824;              // 512
    float*  out     = (float*)d_out;

    k1_wh  <<<dim3(Bx * Ex, Nx / 64), 256, 0, stream>>>(X, Ws, a, Whb, w1, w2);
    k2_att <<<dim3(Nx / 32, Bx * Ex), 256, 0, stream>>>(edges, Whb, w1, w2, Hb);
    k0_convert<<<dim3(HIDx + EMBx), 256, 0, stream>>>(lin0_w, lin1_w, W0T, W1T);
    k3_lin0<<<dim3(512), 256, 0, stream>>>(Hb, W0T, lin0_b, h_pre, partials);
    k3b_stats<<<8, 256, 0, stream>>>(partials, gamma, beta, sb);
    k4_lin1<<<dim3(512), 256, 0, stream>>>(h_pre, sb, W1T, lin1_b, out);
}

// Round 5
// 160.530 us; speedup vs baseline: 2.0476x; 1.0374x over previous
//
#include <hip/hip_runtime.h>

#define Bx 32
#define Nx 512
#define Ex 4
#define Fx 128
#define Gx 64
#define HIDx 256
#define EMBx 128
#define NEDGE 8192

typedef __attribute__((ext_vector_type(8))) short bf16x8;
typedef __attribute__((ext_vector_type(4))) float f32x4;

__device__ __forceinline__ ushort f2bf(float x) {
    unsigned int u = __float_as_uint(x);
    u += 0x7fffu + ((u >> 16) & 1u);
    return (ushort)(u >> 16);
}
__device__ __forceinline__ float bf2f(ushort h) {
    return __uint_as_float(((unsigned int)h) << 16);
}

// ---- K0: W0T[j][k] = bf16(lin0_w[k][j]); W1T[j][k] = bf16(lin1_w[k][j]) ----
__global__ __launch_bounds__(256) void k0_convert(const float* __restrict__ w0,
                                                  const float* __restrict__ w1,
                                                  ushort* __restrict__ W0T,
                                                  ushort* __restrict__ W1T) {
    int j = blockIdx.x, k = threadIdx.x;
    if (j < HIDx) {
        W0T[j * HIDx + k] = f2bf(w0[k * HIDx + j]);
    } else {
        int jj = j - HIDx;
        W1T[jj * HIDx + k] = f2bf(w1[k * EMBx + jj]);
    }
}

// ---- K1: Whb[be,g,m] = bf16(X[b,m,:] @ Ws[e][:,g]); w1/w2 = Wh . a ---------
// 1-D grid, id&3 = e so Ws[e] stays L2-resident on XCDs {e, e+4} (T1).
__global__ __launch_bounds__(256) void k1_wh(const float* __restrict__ X,
                                             const float* __restrict__ Ws,
                                             const float* __restrict__ a,
                                             ushort* __restrict__ Whb,
                                             float* __restrict__ w1,
                                             float* __restrict__ w2) {
    __shared__ float sXT[Fx][68];
    __shared__ float red1[16][68];
    __shared__ float red2[16][68];
    int id = blockIdx.x;
    int e = id & 3;
    int rest = id >> 2;
    int tile = rest & 7;
    int b = rest >> 3;
    int be = b * 4 + e;
    int n0 = tile * 64;
    int tid = threadIdx.x;
    for (int i = tid; i < 64 * Fx; i += 256) {
        int n = i >> 7, k = i & 127;
        sXT[k][n] = X[(size_t)(b * Nx + n0 + n) * Fx + k];
    }
    __syncthreads();
    const float* We = Ws + e * Fx * Gx;
    int gq = tid & 15, nq = tid >> 4;
    int gg = gq * 4, nn = nq * 4;
    float acc[4][4];
    #pragma unroll
    for (int i = 0; i < 4; ++i)
        #pragma unroll
        for (int j = 0; j < 4; ++j) acc[i][j] = 0.f;
    #pragma unroll 4
    for (int k = 0; k < Fx; ++k) {
        float4 av = *(const float4*)&sXT[k][nn];
        float4 bv = *(const float4*)&We[k * Gx + gg];
        float ai[4] = {av.x, av.y, av.z, av.w};
        float bj[4] = {bv.x, bv.y, bv.z, bv.w};
        #pragma unroll
        for (int i = 0; i < 4; ++i)
            #pragma unroll
            for (int j = 0; j < 4; ++j) acc[i][j] += ai[i] * bj[j];
    }
    float a1[4], a2[4];
    #pragma unroll
    for (int j = 0; j < 4; ++j) {
        a1[j] = a[e * 2 * Gx + gg + j];
        a2[j] = a[e * 2 * Gx + Gx + gg + j];
    }
    #pragma unroll
    for (int j = 0; j < 4; ++j) {
        ushort4 v;
        v.x = f2bf(acc[0][j]); v.y = f2bf(acc[1][j]);
        v.z = f2bf(acc[2][j]); v.w = f2bf(acc[3][j]);
        *(ushort4*)&Whb[((size_t)be * Gx + gg + j) * Nx + n0 + nn] = v;
    }
    #pragma unroll
    for (int i = 0; i < 4; ++i) {
        float p1 = acc[i][0] * a1[0] + acc[i][1] * a1[1] + acc[i][2] * a1[2] + acc[i][3] * a1[3];
        float p2 = acc[i][0] * a2[0] + acc[i][1] * a2[1] + acc[i][2] * a2[2] + acc[i][3] * a2[3];
        red1[gq][nn + i] = p1;
        red2[gq][nn + i] = p2;
    }
    __syncthreads();
    if (tid < 64) {
        float s1 = 0.f, s2 = 0.f;
        #pragma unroll
        for (int t = 0; t < 16; ++t) { s1 += red1[t][tid]; s2 += red2[t][tid]; }
        w1[be * Nx + tid + n0] = s1;
        w2[be * Nx + tid + n0] = s2;
    }
}

// ---- K2: counts -> dense bf16 P tile -> MFMA PV -> Hb (bf16) ---------------
// grid (x=be, y=tile): all 16 tiles of a graph land on XCD be%8 -> edges and
// Whb[be] are L2-resident for the whole graph (T1).
__global__ __launch_bounds__(256) void k2_att(const int* __restrict__ edges,
                                              const ushort* __restrict__ Whb,
                                              const float* __restrict__ w1g,
                                              const float* __restrict__ w2g,
                                              ushort* __restrict__ Hb) {
    __shared__ unsigned int cnt[32 * 128];
    __shared__ float sw2[Nx];
    __shared__ float sw1[32];
    __shared__ float sinv[32];
    __shared__ ushort P[32 * 512];
    int be = blockIdx.x; int b = be >> 2; int e = be & 3;
    int n0 = blockIdx.y * 32;
    int tid = threadIdx.x;
    for (int i = tid; i < 32 * 128; i += 256) cnt[i] = 0u;
    for (int i = tid; i < Nx; i += 256) sw2[i] = w2g[be * Nx + i];
    if (tid < 32) sw1[tid] = w1g[be * Nx + n0 + tid];
    __syncthreads();
    const int4* srcp = (const int4*)(edges + (size_t)be * 2 * NEDGE);
    const int4* dstp = (const int4*)(edges + (size_t)be * 2 * NEDGE + NEDGE);
    for (int i = tid; i < NEDGE / 4; i += 256) {
        int4 s4 = srcp[i]; int4 d4 = dstp[i];
        int ss[4] = {s4.x, s4.y, s4.z, s4.w};
        int dd[4] = {d4.x, d4.y, d4.z, d4.w};
        #pragma unroll
        for (int u = 0; u < 4; ++u) {
            unsigned int r = (unsigned int)(ss[u] - n0);
            if (r < 32u) atomicAdd(&cnt[r * 128 + (dd[u] >> 2)], 1u << ((dd[u] & 3) * 8));
        }
    }
    __syncthreads();
    int wave = tid >> 6, lane = tid & 63;
    for (int r = wave; r < 32; r += 4) {
        float w1v = sw1[r];
        unsigned int cw0 = cnt[r * 128 + lane];
        unsigned int cw1 = cnt[r * 128 + 64 + lane];
        float4 s2a = *(const float4*)&sw2[lane * 4];
        float4 s2b = *(const float4*)&sw2[256 + lane * 4];
        int cc[8];
        cc[0] = cw0 & 255; cc[1] = (cw0 >> 8) & 255; cc[2] = (cw0 >> 16) & 255; cc[3] = (cw0 >> 24) & 255;
        cc[4] = cw1 & 255; cc[5] = (cw1 >> 8) & 255; cc[6] = (cw1 >> 16) & 255; cc[7] = (cw1 >> 24) & 255;
        float sc[8];
        sc[0] = (w1v + s2a.x) * (float)cc[0];
        sc[1] = (w1v + s2a.y) * (float)cc[1];
        sc[2] = (w1v + s2a.z) * (float)cc[2];
        sc[3] = (w1v + s2a.w) * (float)cc[3];
        sc[4] = (w1v + s2b.x) * (float)cc[4];
        sc[5] = (w1v + s2b.y) * (float)cc[5];
        sc[6] = (w1v + s2b.z) * (float)cc[6];
        sc[7] = (w1v + s2b.w) * (float)cc[7];
        float mx = 0.f; int K = 0;
        #pragma unroll
        for (int u = 0; u < 8; ++u) {
            if (cc[u]) { mx = fmaxf(mx, sc[u]); K++; }
        }
        #pragma unroll
        for (int off = 32; off > 0; off >>= 1) {
            mx = fmaxf(mx, __shfl_xor(mx, off, 64));
            K += __shfl_xor(K, off, 64);
        }
        float dsum = 0.f;
        ushort pv[8];
        #pragma unroll
        for (int u = 0; u < 8; ++u) {
            if (cc[u]) {
                float ew = __expf(sc[u] - mx);
                dsum += ew;
                pv[u] = f2bf(ew * (float)cc[u]);
            } else pv[u] = 0;
        }
        #pragma unroll
        for (int off = 32; off > 0; off >>= 1) dsum += __shfl_xor(dsum, off, 64);
        if (lane == 0) sinv[r] = 1.f / (dsum + (float)(Nx - K) * __expf(-mx));
        unsigned int swz = (unsigned int)((r & 7) << 4);
        uint2 wlo, whi;
        wlo.x = (unsigned int)pv[0] | ((unsigned int)pv[1] << 16);
        wlo.y = (unsigned int)pv[2] | ((unsigned int)pv[3] << 16);
        whi.x = (unsigned int)pv[4] | ((unsigned int)pv[5] << 16);
        whi.y = (unsigned int)pv[6] | ((unsigned int)pv[7] << 16);
        *(uint2*)((char*)P + (((unsigned)(r * 1024 + lane * 8)) ^ swz)) = wlo;
        *(uint2*)((char*)P + (((unsigned)(r * 1024 + 512 + lane * 8)) ^ swz)) = whi;
    }
    __syncthreads();
    int r0 = (wave >> 1) * 16;
    int c0 = (wave & 1) * 32;
    int row = r0 + (lane & 15);
    int kgrp = lane >> 4;
    f32x4 acc0 = {0.f, 0.f, 0.f, 0.f};
    f32x4 acc1 = {0.f, 0.f, 0.f, 0.f};
    const ushort* WB = Whb + (size_t)be * Gx * Nx;
    int g0 = c0 + (lane & 15);
    const ushort* B0 = WB + (size_t)g0 * Nx + kgrp * 8;
    const ushort* B1 = WB + (size_t)(g0 + 16) * Nx + kgrp * 8;
    unsigned int aswz = (unsigned int)((row & 7) << 4);
    #pragma unroll
    for (int ks = 0; ks < 16; ++ks) {
        unsigned int abyte = ((unsigned)(row * 1024 + ks * 64 + kgrp * 16)) ^ aswz;
        bf16x8 af = *(const bf16x8*)((const char*)P + abyte);
        bf16x8 bf0 = *(const bf16x8*)(B0 + ks * 32);
        bf16x8 bf1 = *(const bf16x8*)(B1 + ks * 32);
        acc0 = __builtin_amdgcn_mfma_f32_16x16x32_bf16(af, bf0, acc0, 0, 0, 0);
        acc1 = __builtin_amdgcn_mfma_f32_16x16x32_bf16(af, bf1, acc1, 0, 0, 0);
    }
    float4 iv = *(const float4*)&sinv[r0 + kgrp * 4];
    float ivv[4] = {iv.x, iv.y, iv.z, iv.w};
    #pragma unroll
    for (int reg = 0; reg < 4; ++reg) {
        int rr = n0 + r0 + kgrp * 4 + reg;
        ushort* Hp = &Hb[((size_t)(b * Nx) + rr) * (Ex * Gx) + e * Gx + c0 + (lane & 15)];
        Hp[0]  = f2bf(acc0[reg] * ivv[reg]);
        Hp[16] = f2bf(acc1[reg] * ivv[reg]);
    }
}

// ---- K3: h_pre = bf16(Hb @ W0 + b) via MFMA; fp32 BN partials --------------
__global__ __launch_bounds__(256) void k3_lin0(const ushort* __restrict__ Hb,
                                               const ushort* __restrict__ W0T,
                                               const float* __restrict__ lin0_b,
                                               ushort* __restrict__ h_pre,
                                               float* __restrict__ partials) {
    __shared__ float red_s[2][256], red_q[2][256];
    int tid = threadIdx.x, wave = tid >> 6, lane = tid & 63;
    int wr = wave >> 1, wc = wave & 1;
    int row0 = blockIdx.x * 32 + wr * 16;
    int arow = lane & 15, kg = lane >> 4;
    const ushort* A = Hb + (size_t)(row0 + arow) * HIDx;
    f32x4 acc[8];
    #pragma unroll
    for (int t = 0; t < 8; ++t) acc[t] = (f32x4){0.f, 0.f, 0.f, 0.f};
    #pragma unroll
    for (int ks = 0; ks < 8; ++ks) {
        int k0 = ks * 32 + kg * 8;
        bf16x8 af = *(const bf16x8*)&A[k0];
        #pragma unroll
        for (int jt = 0; jt < 8; ++jt) {
            bf16x8 bf = *(const bf16x8*)&W0T[(size_t)(wc * 128 + jt * 16 + arow) * HIDx + k0];
            acc[jt] = __builtin_amdgcn_mfma_f32_16x16x32_bf16(af, bf, acc[jt], 0, 0, 0);
        }
    }
    #pragma unroll
    for (int jt = 0; jt < 8; ++jt) {
        int col = wc * 128 + jt * 16 + arow;
        float b = lin0_b[col];
        float s = 0.f, q = 0.f;
        #pragma unroll
        for (int reg = 0; reg < 4; ++reg) {
            float v = acc[jt][reg] + b;
            h_pre[(size_t)(row0 + kg * 4 + reg) * HIDx + col] = f2bf(v);
            s += v; q += v * v;
        }
        s += __shfl_xor(s, 16, 64); s += __shfl_xor(s, 32, 64);
        q += __shfl_xor(q, 16, 64); q += __shfl_xor(q, 32, 64);
        if (lane < 16) { red_s[wr][col] = s; red_q[wr][col] = q; }
    }
    __syncthreads();
    int j = tid;
    partials[(size_t)blockIdx.x * 2 * HIDx + j] = red_s[0][j] + red_s[1][j];
    partials[(size_t)blockIdx.x * 2 * HIDx + HIDx + j] = red_q[0][j] + red_q[1][j];
}

// ---- K3b: finalize BN stats -> scale/bias ----------------------------------
__global__ __launch_bounds__(256) void k3b_stats(const float* __restrict__ partials,
                                                 const float* __restrict__ gamma,
                                                 const float* __restrict__ beta,
                                                 float* __restrict__ sb) {
    __shared__ float rs[8][32], rq[8][32];
    int jl = threadIdx.x & 31, sl = threadIdx.x >> 5;
    int j = blockIdx.x * 32 + jl;
    float s = 0.f, q = 0.f;
    for (int blk = sl; blk < 512; blk += 8) {
        s += partials[blk * 512 + j];
        q += partials[blk * 512 + 256 + j];
    }
    rs[sl][jl] = s; rq[sl][jl] = q;
    __syncthreads();
    if (threadIdx.x < 32) {
        float S = 0.f, Q = 0.f;
        #pragma unroll
        for (int t = 0; t < 8; ++t) { S += rs[t][jl]; Q += rq[t][jl]; }
        const float invM = 1.f / 16384.f;
        float mu = S * invM;
        float var = fmaxf(Q * invM - mu * mu, 0.f);
        float sc = gamma[j] * rsqrtf(var + 1e-5f);
        sb[j] = sc;
        sb[256 + j] = beta[j] - mu * sc;
    }
}

// ---- K4: out = elu(bn(h_pre)) @ W1 + b via MFMA ----------------------------
__global__ __launch_bounds__(256) void k4_lin1(const ushort* __restrict__ h_pre,
                                               const float* __restrict__ sb,
                                               const ushort* __restrict__ W1T,
                                               const float* __restrict__ lin1_b,
                                               float* __restrict__ out) {
    int tid = threadIdx.x, wave = tid >> 6, lane = tid & 63;
    int wr = wave >> 1, wc = wave & 1;
    int row0 = blockIdx.x * 32 + wr * 16;
    int arow = lane & 15, kg = lane >> 4;
    const ushort* A = h_pre + (size_t)(row0 + arow) * HIDx;
    f32x4 acc[4];
    #pragma unroll
    for (int t = 0; t < 4; ++t) acc[t] = (f32x4){0.f, 0.f, 0.f, 0.f};
    #pragma unroll
    for (int ks = 0; ks < 8; ++ks) {
        int k0 = ks * 32 + kg * 8;
        bf16x8 hv = *(const bf16x8*)&A[k0];
        float4 sc0 = *(const float4*)&sb[k0];
        float4 sc1 = *(const float4*)&sb[k0 + 4];
        float4 bi0 = *(const float4*)&sb[256 + k0];
        float4 bi1 = *(const float4*)&sb[256 + k0 + 4];
        float scv[8] = {sc0.x, sc0.y, sc0.z, sc0.w, sc1.x, sc1.y, sc1.z, sc1.w};
        float biv[8] = {bi0.x, bi0.y, bi0.z, bi0.w, bi1.x, bi1.y, bi1.z, bi1.w};
        bf16x8 af;
        #pragma unroll
        for (int u = 0; u < 8; ++u) {
            float v = bf2f((ushort)hv[u]) * scv[u] + biv[u];
            v = v > 0.f ? v : expm1f(v);
            af[u] = (short)f2bf(v);
        }
        #pragma unroll
        for (int jt = 0; jt < 4; ++jt) {
            bf16x8 bf = *(const bf16x8*)&W1T[(size_t)(wc * 64 + jt * 16 + arow) * HIDx + k0];
            acc[jt] = __builtin_amdgcn_mfma_f32_16x16x32_bf16(af, bf, acc[jt], 0, 0, 0);
        }
    }
    #pragma unroll
    for (int jt = 0; jt < 4; ++jt) {
        int col = wc * 64 + jt * 16 + arow;
        float b = lin1_b[col];
        #pragma unroll
        for (int reg = 0; reg < 4; ++reg)
            out[(size_t)(row0 + kg * 4 + reg) * EMBx + col] = acc[jt][reg] + b;
    }
}

extern "C" void kernel_launch(void* const* d_in, const int* in_sizes, int n_in,
                              void* d_out, int out_size, void* d_ws, size_t ws_size,
                              hipStream_t stream) {
    const float* X      = (const float*)d_in[0];
    const int*   edges  = (const int*)d_in[1];
    const float* Ws     = (const float*)d_in[2];
    const float* a      = (const float*)d_in[3];
    const float* lin0_w = (const float*)d_in[4];
    const float* lin0_b = (const float*)d_in[5];
    const float* gamma  = (const float*)d_in[6];
    const float* beta   = (const float*)d_in[7];
    const float* lin1_w = (const float*)d_in[8];
    const float* lin1_b = (const float*)d_in[9];
    float* ws = (float*)d_ws;

    ushort* Whb     = (ushort*)ws;
    ushort* h_pre   = (ushort*)ws;
    ushort* Hb      = (ushort*)(ws + 4194304);
    float*  w1      = ws + 8388608;
    float*  w2      = ws + 8454144;
    ushort* W0T     = (ushort*)(ws + 8388608);   // alias w1/w2: k0 runs after k2
    ushort* W1T     = (ushort*)(ws + 8421376);
    float*  partials= ws + 8519680;
    float*  sb      = ws + 8781824;
    float*  out     = (float*)d_out;

    k1_wh  <<<dim3(1024), 256, 0, stream>>>(X, Ws, a, Whb, w1, w2);
    k2_att <<<dim3(Bx * Ex, Nx / 32), 256, 0, stream>>>(edges, Whb, w1, w2, Hb);
    k0_convert<<<dim3(HIDx + EMBx), 256, 0, stream>>>(lin0_w, lin1_w, W0T, W1T);
    k3_lin0<<<dim3(512), 256, 0, stream>>>(Hb, W0T, lin0_b, h_pre, partials);
    k3b_stats<<<8, 256, 0, stream>>>(partials, gamma, beta, sb);
    k4_lin1<<<dim3(512), 256, 0, stream>>>(h_pre, sb, W1T, lin1_b, out);
}

// Round 6
// 146.932 us; speedup vs baseline: 2.2371x; 1.0925x over previous
//
#include <hip/hip_runtime.h>

#define Bx 32
#define Nx 512
#define Ex 4
#define Fx 128
#define Gx 64
#define HIDx 256
#define EMBx 128
#define NEDGE 8192

typedef __attribute__((ext_vector_type(8))) short bf16x8;
typedef __attribute__((ext_vector_type(4))) float f32x4;

__device__ __forceinline__ ushort f2bf(float x) {
    unsigned int u = __float_as_uint(x);
    u += 0x7fffu + ((u >> 16) & 1u);
    return (ushort)(u >> 16);
}
__device__ __forceinline__ float bf2f(ushort h) {
    return __uint_as_float(((unsigned int)h) << 16);
}

// ---- K0: W0T[j][k] = bf16(lin0_w[k][j]); W1T[j][k] = bf16(lin1_w[k][j]) ----
__global__ __launch_bounds__(256) void k0_convert(const float* __restrict__ w0,
                                                  const float* __restrict__ w1,
                                                  ushort* __restrict__ W0T,
                                                  ushort* __restrict__ W1T) {
    int j = blockIdx.x, k = threadIdx.x;
    if (j < HIDx) {
        W0T[j * HIDx + k] = f2bf(w0[k * HIDx + j]);
    } else {
        int jj = j - HIDx;
        W1T[jj * HIDx + k] = f2bf(w1[k * EMBx + jj]);
    }
}

// ---- K1: Whb[be,g,m] = bf16(X[b,m,:] @ Ws[e][:,g]); w1/w2 = Wh . a ---------
__global__ __launch_bounds__(256) void k1_wh(const float* __restrict__ X,
                                             const float* __restrict__ Ws,
                                             const float* __restrict__ a,
                                             ushort* __restrict__ Whb,
                                             float* __restrict__ w1,
                                             float* __restrict__ w2) {
    __shared__ float sXT[Fx][68];
    __shared__ float red1[16][68];
    __shared__ float red2[16][68];
    int id = blockIdx.x;
    int e = id & 3;
    int rest = id >> 2;
    int tile = rest & 7;
    int b = rest >> 3;
    int be = b * 4 + e;
    int n0 = tile * 64;
    int tid = threadIdx.x;
    for (int i = tid; i < 64 * Fx; i += 256) {
        int n = i >> 7, k = i & 127;
        sXT[k][n] = X[(size_t)(b * Nx + n0 + n) * Fx + k];
    }
    __syncthreads();
    const float* We = Ws + e * Fx * Gx;
    int gq = tid & 15, nq = tid >> 4;
    int gg = gq * 4, nn = nq * 4;
    float acc[4][4];
    #pragma unroll
    for (int i = 0; i < 4; ++i)
        #pragma unroll
        for (int j = 0; j < 4; ++j) acc[i][j] = 0.f;
    #pragma unroll 4
    for (int k = 0; k < Fx; ++k) {
        float4 av = *(const float4*)&sXT[k][nn];
        float4 bv = *(const float4*)&We[k * Gx + gg];
        float ai[4] = {av.x, av.y, av.z, av.w};
        float bj[4] = {bv.x, bv.y, bv.z, bv.w};
        #pragma unroll
        for (int i = 0; i < 4; ++i)
            #pragma unroll
            for (int j = 0; j < 4; ++j) acc[i][j] += ai[i] * bj[j];
    }
    float a1[4], a2[4];
    #pragma unroll
    for (int j = 0; j < 4; ++j) {
        a1[j] = a[e * 2 * Gx + gg + j];
        a2[j] = a[e * 2 * Gx + Gx + gg + j];
    }
    #pragma unroll
    for (int j = 0; j < 4; ++j) {
        ushort4 v;
        v.x = f2bf(acc[0][j]); v.y = f2bf(acc[1][j]);
        v.z = f2bf(acc[2][j]); v.w = f2bf(acc[3][j]);
        *(ushort4*)&Whb[((size_t)be * Gx + gg + j) * Nx + n0 + nn] = v;
    }
    #pragma unroll
    for (int i = 0; i < 4; ++i) {
        float p1 = acc[i][0] * a1[0] + acc[i][1] * a1[1] + acc[i][2] * a1[2] + acc[i][3] * a1[3];
        float p2 = acc[i][0] * a2[0] + acc[i][1] * a2[1] + acc[i][2] * a2[2] + acc[i][3] * a2[3];
        red1[gq][nn + i] = p1;
        red2[gq][nn + i] = p2;
    }
    __syncthreads();
    if (tid < 64) {
        float s1 = 0.f, s2 = 0.f;
        #pragma unroll
        for (int t = 0; t < 16; ++t) { s1 += red1[t][tid]; s2 += red2[t][tid]; }
        w1[be * Nx + tid + n0] = s1;
        w2[be * Nx + tid + n0] = s2;
    }
}

// ---- K2: counts -> row-parallel softmax -> dense bf16 P -> MFMA PV ---------
// 512 threads. cnt (stride-132 words) unions with P (cnt preloaded to regs
// before P overwrite). grid (x=be, y=tile) keeps graph data on one XCD (T1).
__global__ __launch_bounds__(512) void k2_att(const int* __restrict__ edges,
                                              const ushort* __restrict__ Whb,
                                              const float* __restrict__ w1g,
                                              const float* __restrict__ w2g,
                                              ushort* __restrict__ Hb) {
    __shared__ ushort P[32 * 512];          // 32KB; first 16.9KB doubles as cnt
    __shared__ float sw2s[512];             // XOR-swizzled copy of w2 row
    __shared__ float sw1[32];
    __shared__ float sinv[32];
    unsigned int* cnt = (unsigned int*)P;   // [32][132] byte-counter words
    int be = blockIdx.x; int b = be >> 2; int e = be & 3;
    int n0 = blockIdx.y * 32;
    int tid = threadIdx.x;
    for (int i = tid; i < 32 * 132; i += 512) cnt[i] = 0u;
    sw2s[tid ^ (((tid >> 5) & 7) << 2)] = w2g[be * Nx + tid];
    if (tid < 32) sw1[tid] = w1g[be * Nx + n0 + tid];
    __syncthreads();
    // ---- phase 2: edge scan -> packed byte counters ------------------------
    const int4* srcp = (const int4*)(edges + (size_t)be * 2 * NEDGE);
    const int4* dstp = (const int4*)(edges + (size_t)be * 2 * NEDGE + NEDGE);
    for (int i = tid; i < NEDGE / 4; i += 512) {
        int4 s4 = srcp[i]; int4 d4 = dstp[i];
        int ss[4] = {s4.x, s4.y, s4.z, s4.w};
        int dd[4] = {d4.x, d4.y, d4.z, d4.w};
        #pragma unroll
        for (int u = 0; u < 4; ++u) {
            unsigned int r = (unsigned int)(ss[u] - n0);
            if (r < 32u) atomicAdd(&cnt[r * 132 + (dd[u] >> 2)], 1u << ((dd[u] & 3) * 8));
        }
    }
    __syncthreads();
    // ---- phase 3: row-parallel softmax (32 rows x 16 lanes) ----------------
    int r = tid >> 4, c = tid & 15;
    unsigned int w0_[8];
    const unsigned int* crow = cnt + r * 132 + c * 8;
    #pragma unroll
    for (int i = 0; i < 8; ++i) w0_[i] = crow[i];
    float w1v = sw1[r];
    float mx = 0.f; int K = 0;
    #pragma unroll
    for (int t = 0; t < 8; ++t) {
        unsigned int cw = w0_[t];
        int m0 = c * 32 + t * 4;
        float4 s2 = *(const float4*)&sw2s[m0 ^ ((c & 7) << 2)];
        float ssv[4] = {s2.x, s2.y, s2.z, s2.w};
        #pragma unroll
        for (int jj = 0; jj < 4; ++jj) {
            int cc = (cw >> (jj * 8)) & 255;
            if (cc) { mx = fmaxf(mx, (w1v + ssv[jj]) * (float)cc); K++; }
        }
    }
    #pragma unroll
    for (int off = 1; off < 16; off <<= 1) {
        mx = fmaxf(mx, __shfl_xor(mx, off, 64));
        K += __shfl_xor(K, off, 64);
    }
    __syncthreads();   // all cnt words are in registers; P may now overwrite
    float dsum = 0.f;
    #pragma unroll
    for (int tp = 0; tp < 4; ++tp) {
        unsigned int pkw[4];
        #pragma unroll
        for (int h = 0; h < 2; ++h) {
            unsigned int cw = (h == 0) ? w0_[tp * 2] : w0_[tp * 2 + 1];
            int m0 = c * 32 + (tp * 2 + h) * 4;
            float4 s2 = *(const float4*)&sw2s[m0 ^ ((c & 7) << 2)];
            float ssv[4] = {s2.x, s2.y, s2.z, s2.w};
            unsigned int lo = 0, hi = 0;
            #pragma unroll
            for (int jj = 0; jj < 4; ++jj) {
                int cc = (cw >> (jj * 8)) & 255;
                float s = (w1v + ssv[jj]) * (float)cc;
                float ew = __expf(s - mx);
                ew = cc ? ew : 0.f;
                dsum += ew;
                unsigned int pb = cc ? (unsigned int)f2bf(ew * (float)cc) : 0u;
                if (jj & 2) hi |= pb << ((jj & 1) * 16);
                else        lo |= pb << ((jj & 1) * 16);
            }
            pkw[h * 2] = lo; pkw[h * 2 + 1] = hi;
        }
        uint4 pk = {pkw[0], pkw[1], pkw[2], pkw[3]};
        unsigned int byteo = ((unsigned int)(r * 1024 + c * 64 + tp * 16)) ^ ((unsigned int)(r & 7) << 4);
        *(uint4*)((char*)P + byteo) = pk;
    }
    #pragma unroll
    for (int off = 1; off < 16; off <<= 1) dsum += __shfl_xor(dsum, off, 64);
    if (c == 0) sinv[r] = 1.f / (dsum + (float)(Nx - K) * __expf(-mx));
    __syncthreads();
    // ---- phase 4: H-tile = P @ Whb (8 waves, one 16x16 sub-tile each) ------
    int wave = tid >> 6, lane = tid & 63;
    int wr = wave >> 2, wc = wave & 3;
    int row = wr * 16 + (lane & 15);
    int kgrp = lane >> 4;
    f32x4 acc = {0.f, 0.f, 0.f, 0.f};
    const ushort* WB = Whb + (size_t)be * Gx * Nx;
    int g0 = wc * 16 + (lane & 15);
    const ushort* Bp = WB + (size_t)g0 * Nx + kgrp * 8;
    unsigned int aswz = ((unsigned int)(row & 7)) << 4;
    #pragma unroll
    for (int ks = 0; ks < 16; ++ks) {
        unsigned int abyte = ((unsigned int)(row * 1024 + ks * 64 + kgrp * 16)) ^ aswz;
        bf16x8 af = *(const bf16x8*)((const char*)P + abyte);
        bf16x8 bfv = *(const bf16x8*)(Bp + ks * 32);
        acc = __builtin_amdgcn_mfma_f32_16x16x32_bf16(af, bfv, acc, 0, 0, 0);
    }
    float4 iv = *(const float4*)&sinv[wr * 16 + kgrp * 4];
    float ivv[4] = {iv.x, iv.y, iv.z, iv.w};
    #pragma unroll
    for (int reg = 0; reg < 4; ++reg) {
        int rr = n0 + wr * 16 + kgrp * 4 + reg;
        Hb[((size_t)(b * Nx) + rr) * (Ex * Gx) + e * Gx + wc * 16 + (lane & 15)] =
            f2bf(acc[reg] * ivv[reg]);
    }
}

// ---- K3: h_pre = bf16(Hb @ W0 + b) via MFMA; fp32 BN partials --------------
__global__ __launch_bounds__(256) void k3_lin0(const ushort* __restrict__ Hb,
                                               const ushort* __restrict__ W0T,
                                               const float* __restrict__ lin0_b,
                                               ushort* __restrict__ h_pre,
                                               float* __restrict__ partials) {
    __shared__ float red_s[2][256], red_q[2][256];
    int tid = threadIdx.x, wave = tid >> 6, lane = tid & 63;
    int wr = wave >> 1, wc = wave & 1;
    int row0 = blockIdx.x * 32 + wr * 16;
    int arow = lane & 15, kg = lane >> 4;
    const ushort* A = Hb + (size_t)(row0 + arow) * HIDx;
    f32x4 acc[8];
    #pragma unroll
    for (int t = 0; t < 8; ++t) acc[t] = (f32x4){0.f, 0.f, 0.f, 0.f};
    #pragma unroll
    for (int ks = 0; ks < 8; ++ks) {
        int k0 = ks * 32 + kg * 8;
        bf16x8 af = *(const bf16x8*)&A[k0];
        #pragma unroll
        for (int jt = 0; jt < 8; ++jt) {
            bf16x8 bf = *(const bf16x8*)&W0T[(size_t)(wc * 128 + jt * 16 + arow) * HIDx + k0];
            acc[jt] = __builtin_amdgcn_mfma_f32_16x16x32_bf16(af, bf, acc[jt], 0, 0, 0);
        }
    }
    #pragma unroll
    for (int jt = 0; jt < 8; ++jt) {
        int col = wc * 128 + jt * 16 + arow;
        float b = lin0_b[col];
        float s = 0.f, q = 0.f;
        #pragma unroll
        for (int reg = 0; reg < 4; ++reg) {
            float v = acc[jt][reg] + b;
            h_pre[(size_t)(row0 + kg * 4 + reg) * HIDx + col] = f2bf(v);
            s += v; q += v * v;
        }
        s += __shfl_xor(s, 16, 64); s += __shfl_xor(s, 32, 64);
        q += __shfl_xor(q, 16, 64); q += __shfl_xor(q, 32, 64);
        if (lane < 16) { red_s[wr][col] = s; red_q[wr][col] = q; }
    }
    __syncthreads();
    int j = tid;
    partials[(size_t)blockIdx.x * 2 * HIDx + j] = red_s[0][j] + red_s[1][j];
    partials[(size_t)blockIdx.x * 2 * HIDx + HIDx + j] = red_q[0][j] + red_q[1][j];
}

// ---- K3b: finalize BN stats -> scale/bias ----------------------------------
__global__ __launch_bounds__(256) void k3b_stats(const float* __restrict__ partials,
                                                 const float* __restrict__ gamma,
                                                 const float* __restrict__ beta,
                                                 float* __restrict__ sb) {
    __shared__ float rs[8][32], rq[8][32];
    int jl = threadIdx.x & 31, sl = threadIdx.x >> 5;
    int j = blockIdx.x * 32 + jl;
    float s = 0.f, q = 0.f;
    for (int blk = sl; blk < 512; blk += 8) {
        s += partials[blk * 512 + j];
        q += partials[blk * 512 + 256 + j];
    }
    rs[sl][jl] = s; rq[sl][jl] = q;
    __syncthreads();
    if (threadIdx.x < 32) {
        float S = 0.f, Q = 0.f;
        #pragma unroll
        for (int t = 0; t < 8; ++t) { S += rs[t][jl]; Q += rq[t][jl]; }
        const float invM = 1.f / 16384.f;
        float mu = S * invM;
        float var = fmaxf(Q * invM - mu * mu, 0.f);
        float sc = gamma[j] * rsqrtf(var + 1e-5f);
        sb[j] = sc;
        sb[256 + j] = beta[j] - mu * sc;
    }
}

// ---- K4: out = elu(bn(h_pre)) @ W1 + b via MFMA ----------------------------
__global__ __launch_bounds__(256) void k4_lin1(const ushort* __restrict__ h_pre,
                                               const float* __restrict__ sb,
                                               const ushort* __restrict__ W1T,
                                               const float* __restrict__ lin1_b,
                                               float* __restrict__ out) {
    int tid = threadIdx.x, wave = tid >> 6, lane = tid & 63;
    int wr = wave >> 1, wc = wave & 1;
    int row0 = blockIdx.x * 32 + wr * 16;
    int arow = lane & 15, kg = lane >> 4;
    const ushort* A = h_pre + (size_t)(row0 + arow) * HIDx;
    f32x4 acc[4];
    #pragma unroll
    for (int t = 0; t < 4; ++t) acc[t] = (f32x4){0.f, 0.f, 0.f, 0.f};
    #pragma unroll
    for (int ks = 0; ks < 8; ++ks) {
        int k0 = ks * 32 + kg * 8;
        bf16x8 hv = *(const bf16x8*)&A[k0];
        float4 sc0 = *(const float4*)&sb[k0];
        float4 sc1 = *(const float4*)&sb[k0 + 4];
        float4 bi0 = *(const float4*)&sb[256 + k0];
        float4 bi1 = *(const float4*)&sb[256 + k0 + 4];
        float scv[8] = {sc0.x, sc0.y, sc0.z, sc0.w, sc1.x, sc1.y, sc1.z, sc1.w};
        float biv[8] = {bi0.x, bi0.y, bi0.z, bi0.w, bi1.x, bi1.y, bi1.z, bi1.w};
        bf16x8 af;
        #pragma unroll
        for (int u = 0; u < 8; ++u) {
            float v = bf2f((ushort)hv[u]) * scv[u] + biv[u];
            v = v > 0.f ? v : expm1f(v);
            af[u] = (short)f2bf(v);
        }
        #pragma unroll
        for (int jt = 0; jt < 4; ++jt) {
            bf16x8 bf = *(const bf16x8*)&W1T[(size_t)(wc * 64 + jt * 16 + arow) * HIDx + k0];
            acc[jt] = __builtin_amdgcn_mfma_f32_16x16x32_bf16(af, bf, acc[jt], 0, 0, 0);
        }
    }
    #pragma unroll
    for (int jt = 0; jt < 4; ++jt) {
        int col = wc * 64 + jt * 16 + arow;
        float b = lin1_b[col];
        #pragma unroll
        for (int reg = 0; reg < 4; ++reg)
            out[(size_t)(row0 + kg * 4 + reg) * EMBx + col] = acc[jt][reg] + b;
    }
}

extern "C" void kernel_launch(void* const* d_in, const int* in_sizes, int n_in,
                              void* d_out, int out_size, void* d_ws, size_t ws_size,
                              hipStream_t stream) {
    const float* X      = (const float*)d_in[0];
    const int*   edges  = (const int*)d_in[1];
    const float* Ws     = (const float*)d_in[2];
    const float* a      = (const float*)d_in[3];
    const float* lin0_w = (const float*)d_in[4];
    const float* lin0_b = (const float*)d_in[5];
    const float* gamma  = (const float*)d_in[6];
    const float* beta   = (const float*)d_in[7];
    const float* lin1_w = (const float*)d_in[8];
    const float* lin1_b = (const float*)d_in[9];
    float* ws = (float*)d_ws;

    ushort* Whb     = (ushort*)ws;
    ushort* h_pre   = (ushort*)ws;
    ushort* Hb      = (ushort*)(ws + 4194304);
    float*  w1      = ws + 8388608;
    float*  w2      = ws + 8454144;
    ushort* W0T     = (ushort*)(ws + 8388608);   // alias w1/w2: k0 runs after k2
    ushort* W1T     = (ushort*)(ws + 8421376);
    float*  partials= ws + 8519680;
    float*  sb      = ws + 8781824;
    float*  out     = (float*)d_out;

    k1_wh  <<<dim3(1024), 256, 0, stream>>>(X, Ws, a, Whb, w1, w2);
    k2_att <<<dim3(Bx * Ex, Nx / 32), 512, 0, stream>>>(edges, Whb, w1, w2, Hb);
    k0_convert<<<dim3(HIDx + EMBx), 256, 0, stream>>>(lin0_w, lin1_w, W0T, W1T);
    k3_lin0<<<dim3(512), 256, 0, stream>>>(Hb, W0T, lin0_b, h_pre, partials);
    k3b_stats<<<8, 256, 0, stream>>>(partials, gamma, beta, sb);
    k4_lin1<<<dim3(512), 256, 0, stream>>>(h_pre, sb, W1T, lin1_b, out);
}

// Round 7
// 130.534 us; speedup vs baseline: 2.5181x; 1.1256x over previous
//
#include <hip/hip_runtime.h>

#define Bx 32
#define Nx 512
#define Ex 4
#define Fx 128
#define Gx 64
#define HIDx 256
#define EMBx 128
#define NEDGE 8192

typedef __attribute__((ext_vector_type(8))) short bf16x8;
typedef __attribute__((ext_vector_type(4))) float f32x4;

#define L2E 1.44269504f

__device__ __forceinline__ ushort f2bf(float x) {
    unsigned int u = __float_as_uint(x);
    u += 0x7fffu + ((u >> 16) & 1u);
    return (ushort)(u >> 16);
}
__device__ __forceinline__ float bf2f(ushort h) {
    return __uint_as_float(((unsigned int)h) << 16);
}

// ---- K0: transpose/cast weights. W0T[j][k], W1T[j][k], WsT[e][g][f] --------
__global__ __launch_bounds__(256) void k0_convert(const float* __restrict__ w0,
                                                  const float* __restrict__ w1f,
                                                  const float* __restrict__ Wsf,
                                                  ushort* __restrict__ W0T,
                                                  ushort* __restrict__ W1T,
                                                  ushort* __restrict__ WsT) {
    int j = blockIdx.x, k = threadIdx.x;
    if (j < HIDx) {
        W0T[j * HIDx + k] = f2bf(w0[k * HIDx + j]);
    } else if (j < HIDx + EMBx) {
        int jj = j - HIDx;
        W1T[jj * HIDx + k] = f2bf(w1f[k * EMBx + jj]);
    } else {
        int eg = j - (HIDx + EMBx);      // 0..255 = e*64+g
        if (k < Fx) {
            int e = eg >> 6, g = eg & 63;
            WsT[eg * Fx + k] = f2bf(Wsf[(e * Fx + k) * Gx + g]);
        }
    }
}

// ---- K1: Whb[be,g,m] = bf16(X @ Ws) via MFMA; w1/w2 = Wh . a ---------------
__global__ __launch_bounds__(256) void k1_wh(const float* __restrict__ X,
                                             const ushort* __restrict__ WsT,
                                             const float* __restrict__ a,
                                             ushort* __restrict__ Whb,
                                             float* __restrict__ w1,
                                             float* __restrict__ w2) {
    __shared__ ushort sXb[64 * 128];   // 16KB, XOR-swizzled bf16 A tile
    int id = blockIdx.x;
    int e = id & 3;
    int rest = id >> 2;
    int tile = rest & 7;
    int b = rest >> 3;
    int be = b * 4 + e;
    int n0 = tile * 64;
    int tid = threadIdx.x;
    // stage X (f32 -> bf16, swizzled rows of 256B)
    for (int i = tid; i < 2048; i += 256) {
        int row = i >> 5, kq = i & 31;
        float4 xv = *(const float4*)&X[(size_t)(b * Nx + n0 + row) * Fx + kq * 4];
        ushort4 hv;
        hv.x = f2bf(xv.x); hv.y = f2bf(xv.y); hv.z = f2bf(xv.z); hv.w = f2bf(xv.w);
        unsigned int byteo = ((unsigned int)(row * 256 + kq * 8)) ^ (((unsigned int)(row & 7)) << 4);
        *(ushort4*)((char*)sXb + byteo) = hv;
    }
    __syncthreads();
    int wave = tid >> 6, lane = tid & 63;
    int arow = lane & 15, kg = lane >> 4;
    int row = wave * 16 + arow;
    f32x4 acc[4];
    #pragma unroll
    for (int t = 0; t < 4; ++t) acc[t] = (f32x4){0.f, 0.f, 0.f, 0.f};
    const ushort* WT = WsT + e * Gx * Fx;   // [g][f]
    unsigned int aswz = ((unsigned int)(row & 7)) << 4;
    #pragma unroll
    for (int ks = 0; ks < 4; ++ks) {
        unsigned int abyte = ((unsigned int)(row * 256 + ks * 64 + kg * 16)) ^ aswz;
        bf16x8 af = *(const bf16x8*)((const char*)sXb + abyte);
        #pragma unroll
        for (int jt = 0; jt < 4; ++jt) {
            bf16x8 bf = *(const bf16x8*)&WT[(size_t)(jt * 16 + arow) * Fx + ks * 32 + kg * 8];
            acc[jt] = __builtin_amdgcn_mfma_f32_16x16x32_bf16(af, bf, acc[jt], 0, 0, 0);
        }
    }
    // epilogue: C row m = wave*16 + kg*4 + reg, col g = jt*16 + arow
    float a1v[4], a2v[4];
    #pragma unroll
    for (int jt = 0; jt < 4; ++jt) {
        a1v[jt] = a[e * 2 * Gx + jt * 16 + arow];
        a2v[jt] = a[e * 2 * Gx + Gx + jt * 16 + arow];
    }
    int m0 = n0 + wave * 16 + kg * 4;
    #pragma unroll
    for (int jt = 0; jt < 4; ++jt) {
        int g = jt * 16 + arow;
        ushort4 v;
        v.x = f2bf(acc[jt][0]); v.y = f2bf(acc[jt][1]);
        v.z = f2bf(acc[jt][2]); v.w = f2bf(acc[jt][3]);
        *(ushort4*)&Whb[((size_t)be * Gx + g) * Nx + m0] = v;
    }
    #pragma unroll
    for (int reg = 0; reg < 4; ++reg) {
        float p1 = acc[0][reg] * a1v[0] + acc[1][reg] * a1v[1] + acc[2][reg] * a1v[2] + acc[3][reg] * a1v[3];
        float p2 = acc[0][reg] * a2v[0] + acc[1][reg] * a2v[1] + acc[2][reg] * a2v[2] + acc[3][reg] * a2v[3];
        #pragma unroll
        for (int off = 1; off < 16; off <<= 1) {
            p1 += __shfl_xor(p1, off, 64);
            p2 += __shfl_xor(p2, off, 64);
        }
        if (arow == 0) {
            w1[be * Nx + m0 + reg] = p1;
            w2[be * Nx + m0 + reg] = p2;
        }
    }
}

// ---- K2: counts -> shift-free single-pass softmax -> bf16 P -> MFMA PV -----
__global__ __launch_bounds__(512) void k2_att(const int* __restrict__ edges,
                                              const ushort* __restrict__ Whb,
                                              const float* __restrict__ w1g,
                                              const float* __restrict__ w2g,
                                              ushort* __restrict__ Hb) {
    __shared__ ushort P[32 * 512];          // 32KB; first 16.9KB doubles as cnt
    __shared__ float sw2s[512];             // XOR-swizzled, pre-scaled by log2e
    __shared__ float sw1[32];               // pre-scaled by log2e
    __shared__ float sinv[32];
    unsigned int* cnt = (unsigned int*)P;   // [32][132]
    int be = blockIdx.x; int b = be >> 2; int e = be & 3;
    int n0 = blockIdx.y * 32;
    int tid = threadIdx.x;
    for (int i = tid; i < 32 * 132; i += 512) cnt[i] = 0u;
    sw2s[tid ^ (((tid >> 5) & 7) << 2)] = w2g[be * Nx + tid] * L2E;
    if (tid < 32) sw1[tid] = w1g[be * Nx + n0 + tid] * L2E;
    __syncthreads();
    // phase 2: edge scan -> packed byte counters
    const int4* srcp = (const int4*)(edges + (size_t)be * 2 * NEDGE);
    const int4* dstp = (const int4*)(edges + (size_t)be * 2 * NEDGE + NEDGE);
    for (int i = tid; i < NEDGE / 4; i += 512) {
        int4 s4 = srcp[i]; int4 d4 = dstp[i];
        int ss[4] = {s4.x, s4.y, s4.z, s4.w};
        int dd[4] = {d4.x, d4.y, d4.z, d4.w};
        #pragma unroll
        for (int u = 0; u < 4; ++u) {
            unsigned int r = (unsigned int)(ss[u] - n0);
            if (r < 32u) atomicAdd(&cnt[r * 132 + (dd[u] >> 2)], 1u << ((dd[u] & 3) * 8));
        }
    }
    __syncthreads();
    // phase 3: single-pass softmax (shift 0), 32 rows x 16 lanes
    int r = tid >> 4, c = tid & 15;
    unsigned int cw[8];
    const unsigned int* crow = cnt + r * 132 + c * 8;
    #pragma unroll
    for (int i = 0; i < 8; ++i) cw[i] = crow[i];
    float w1v = sw1[r];
    __syncthreads();   // cnt consumed; P may overwrite
    float dsum = 0.f; int K = 0;
    #pragma unroll
    for (int tp = 0; tp < 4; ++tp) {
        unsigned int pkw[4];
        #pragma unroll
        for (int h = 0; h < 2; ++h) {
            unsigned int w = cw[tp * 2 + h];
            unsigned int nzm = (w | ((w & 0x7f7f7f7fu) + 0x7f7f7f7fu)) & 0x80808080u;
            K += __popc(nzm);
            int m0 = c * 32 + (tp * 2 + h) * 4;
            float4 s2 = *(const float4*)&sw2s[m0 ^ ((c & 7) << 2)];
            float sv[4] = {s2.x, s2.y, s2.z, s2.w};
            unsigned int lo = 0, hi = 0;
            #pragma unroll
            for (int jj = 0; jj < 4; ++jj) {
                unsigned int ccu = (w >> (jj * 8)) & 255u;
                float cf = (float)ccu;
                float ew = __builtin_exp2f(fminf((w1v + sv[jj]) * cf, 120.f));
                dsum += ccu ? ew : 0.f;
                unsigned int pb = (unsigned int)f2bf(ew * cf);   // cc=0 -> 0
                if (jj & 2) hi |= pb << ((jj & 1) * 16);
                else        lo |= pb << ((jj & 1) * 16);
            }
            pkw[h * 2] = lo; pkw[h * 2 + 1] = hi;
        }
        uint4 pk = {pkw[0], pkw[1], pkw[2], pkw[3]};
        unsigned int byteo = ((unsigned int)(r * 1024 + c * 64 + tp * 16)) ^ (((unsigned int)(r & 7)) << 4);
        *(uint4*)((char*)P + byteo) = pk;
    }
    #pragma unroll
    for (int off = 1; off < 16; off <<= 1) {
        dsum += __shfl_xor(dsum, off, 64);
        K += __shfl_xor(K, off, 64);
    }
    if (c == 0) sinv[r] = 1.f / (dsum + (float)(Nx - K));
    __syncthreads();
    // phase 4: H-tile = P @ Whb (8 waves, one 16x16 sub-tile each)
    int wave = tid >> 6, lane = tid & 63;
    int wr = wave >> 2, wc = wave & 3;
    int row = wr * 16 + (lane & 15);
    int kgrp = lane >> 4;
    f32x4 acc = {0.f, 0.f, 0.f, 0.f};
    const ushort* WB = Whb + (size_t)be * Gx * Nx;
    int g0 = wc * 16 + (lane & 15);
    const ushort* Bp = WB + (size_t)g0 * Nx + kgrp * 8;
    unsigned int aswz = ((unsigned int)(row & 7)) << 4;
    __builtin_amdgcn_s_setprio(1);
    #pragma unroll
    for (int ks = 0; ks < 16; ++ks) {
        unsigned int abyte = ((unsigned int)(row * 1024 + ks * 64 + kgrp * 16)) ^ aswz;
        bf16x8 af = *(const bf16x8*)((const char*)P + abyte);
        bf16x8 bfv = *(const bf16x8*)(Bp + ks * 32);
        acc = __builtin_amdgcn_mfma_f32_16x16x32_bf16(af, bfv, acc, 0, 0, 0);
    }
    __builtin_amdgcn_s_setprio(0);
    float4 iv = *(const float4*)&sinv[wr * 16 + kgrp * 4];
    float ivv[4] = {iv.x, iv.y, iv.z, iv.w};
    #pragma unroll
    for (int reg = 0; reg < 4; ++reg) {
        int rr = n0 + wr * 16 + kgrp * 4 + reg;
        Hb[((size_t)(b * Nx) + rr) * (Ex * Gx) + e * Gx + wc * 16 + (lane & 15)] =
            f2bf(acc[reg] * ivv[reg]);
    }
}

// ---- K3: h_pre = bf16(Hb @ W0 + b) via MFMA; fp32 BN partials --------------
__global__ __launch_bounds__(256) void k3_lin0(const ushort* __restrict__ Hb,
                                               const ushort* __restrict__ W0T,
                                               const float* __restrict__ lin0_b,
                                               ushort* __restrict__ h_pre,
                                               float* __restrict__ partials) {
    __shared__ float red_s[2][256], red_q[2][256];
    int tid = threadIdx.x, wave = tid >> 6, lane = tid & 63;
    int wr = wave >> 1, wc = wave & 1;
    int row0 = blockIdx.x * 32 + wr * 16;
    int arow = lane & 15, kg = lane >> 4;
    const ushort* A = Hb + (size_t)(row0 + arow) * HIDx;
    f32x4 acc[8];
    #pragma unroll
    for (int t = 0; t < 8; ++t) acc[t] = (f32x4){0.f, 0.f, 0.f, 0.f};
    #pragma unroll
    for (int ks = 0; ks < 8; ++ks) {
        int k0 = ks * 32 + kg * 8;
        bf16x8 af = *(const bf16x8*)&A[k0];
        #pragma unroll
        for (int jt = 0; jt < 8; ++jt) {
            bf16x8 bf = *(const bf16x8*)&W0T[(size_t)(wc * 128 + jt * 16 + arow) * HIDx + k0];
            acc[jt] = __builtin_amdgcn_mfma_f32_16x16x32_bf16(af, bf, acc[jt], 0, 0, 0);
        }
    }
    #pragma unroll
    for (int jt = 0; jt < 8; ++jt) {
        int col = wc * 128 + jt * 16 + arow;
        float b = lin0_b[col];
        float s = 0.f, q = 0.f;
        #pragma unroll
        for (int reg = 0; reg < 4; ++reg) {
            float v = acc[jt][reg] + b;
            h_pre[(size_t)(row0 + kg * 4 + reg) * HIDx + col] = f2bf(v);
            s += v; q += v * v;
        }
        s += __shfl_xor(s, 16, 64); s += __shfl_xor(s, 32, 64);
        q += __shfl_xor(q, 16, 64); q += __shfl_xor(q, 32, 64);
        if (lane < 16) { red_s[wr][col] = s; red_q[wr][col] = q; }
    }
    __syncthreads();
    int j = tid;
    partials[(size_t)blockIdx.x * 2 * HIDx + j] = red_s[0][j] + red_s[1][j];
    partials[(size_t)blockIdx.x * 2 * HIDx + HIDx + j] = red_q[0][j] + red_q[1][j];
}

// ---- K3b: finalize BN stats -> scale/bias ----------------------------------
__global__ __launch_bounds__(256) void k3b_stats(const float* __restrict__ partials,
                                                 const float* __restrict__ gamma,
                                                 const float* __restrict__ beta,
                                                 float* __restrict__ sb) {
    __shared__ float rs[8][32], rq[8][32];
    int jl = threadIdx.x & 31, sl = threadIdx.x >> 5;
    int j = blockIdx.x * 32 + jl;
    float s = 0.f, q = 0.f;
    for (int blk = sl; blk < 512; blk += 8) {
        s += partials[blk * 512 + j];
        q += partials[blk * 512 + 256 + j];
    }
    rs[sl][jl] = s; rq[sl][jl] = q;
    __syncthreads();
    if (threadIdx.x < 32) {
        float S = 0.f, Q = 0.f;
        #pragma unroll
        for (int t = 0; t < 8; ++t) { S += rs[t][jl]; Q += rq[t][jl]; }
        const float invM = 1.f / 16384.f;
        float mu = S * invM;
        float var = fmaxf(Q * invM - mu * mu, 0.f);
        float sc = gamma[j] * rsqrtf(var + 1e-5f);
        sb[j] = sc;
        sb[256 + j] = beta[j] - mu * sc;
    }
}

// ---- K4: out = elu(bn(h_pre)) @ W1 + b via MFMA ----------------------------
__global__ __launch_bounds__(256) void k4_lin1(const ushort* __restrict__ h_pre,
                                               const float* __restrict__ sb,
                                               const ushort* __restrict__ W1T,
                                               const float* __restrict__ lin1_b,
                                               float* __restrict__ out) {
    int tid = threadIdx.x, wave = tid >> 6, lane = tid & 63;
    int wr = wave >> 1, wc = wave & 1;
    int row0 = blockIdx.x * 32 + wr * 16;
    int arow = lane & 15, kg = lane >> 4;
    const ushort* A = h_pre + (size_t)(row0 + arow) * HIDx;
    f32x4 acc[4];
    #pragma unroll
    for (int t = 0; t < 4; ++t) acc[t] = (f32x4){0.f, 0.f, 0.f, 0.f};
    #pragma unroll
    for (int ks = 0; ks < 8; ++ks) {
        int k0 = ks * 32 + kg * 8;
        bf16x8 hv = *(const bf16x8*)&A[k0];
        float4 sc0 = *(const float4*)&sb[k0];
        float4 sc1 = *(const float4*)&sb[k0 + 4];
        float4 bi0 = *(const float4*)&sb[256 + k0];
        float4 bi1 = *(const float4*)&sb[256 + k0 + 4];
        float scv[8] = {sc0.x, sc0.y, sc0.z, sc0.w, sc1.x, sc1.y, sc1.z, sc1.w};
        float biv[8] = {bi0.x, bi0.y, bi0.z, bi0.w, bi1.x, bi1.y, bi1.z, bi1.w};
        bf16x8 af;
        #pragma unroll
        for (int u = 0; u < 8; ++u) {
            float v = bf2f((ushort)hv[u]) * scv[u] + biv[u];
            v = v > 0.f ? v : expm1f(v);
            af[u] = (short)f2bf(v);
        }
        #pragma unroll
        for (int jt = 0; jt < 4; ++jt) {
            bf16x8 bf = *(const bf16x8*)&W1T[(size_t)(wc * 64 + jt * 16 + arow) * HIDx + k0];
            acc[jt] = __builtin_amdgcn_mfma_f32_16x16x32_bf16(af, bf, acc[jt], 0, 0, 0);
        }
    }
    #pragma unroll
    for (int jt = 0; jt < 4; ++jt) {
        int col = wc * 64 + jt * 16 + arow;
        float b = lin1_b[col];
        #pragma unroll
        for (int reg = 0; reg < 4; ++reg)
            out[(size_t)(row0 + kg * 4 + reg) * EMBx + col] = acc[jt][reg] + b;
    }
}

extern "C" void kernel_launch(void* const* d_in, const int* in_sizes, int n_in,
                              void* d_out, int out_size, void* d_ws, size_t ws_size,
                              hipStream_t stream) {
    const float* X      = (const float*)d_in[0];
    const int*   edges  = (const int*)d_in[1];
    const float* Ws     = (const float*)d_in[2];
    const float* a      = (const float*)d_in[3];
    const float* lin0_w = (const float*)d_in[4];
    const float* lin0_b = (const float*)d_in[5];
    const float* gamma  = (const float*)d_in[6];
    const float* beta   = (const float*)d_in[7];
    const float* lin1_w = (const float*)d_in[8];
    const float* lin1_b = (const float*)d_in[9];
    float* ws = (float*)d_ws;

    ushort* Whb     = (ushort*)ws;               // region0: Whb then h_pre
    ushort* h_pre   = (ushort*)ws;
    ushort* Hb      = (ushort*)(ws + 4194304);
    float*  w1      = ws + 8388608;              // 65,536
    float*  w2      = ws + 8454144;              // 65,536
    float*  partials= ws + 8519680;              // 262,144
    float*  sb      = ws + 8781824;              // 512
    ushort* WsT     = (ushort*)(ws + 8782336);   // 32,768 ushorts
    ushort* W0T     = (ushort*)(ws + 8798720);   // 65,536 ushorts
    ushort* W1T     = (ushort*)(ws + 8831488);   // 32,768 ushorts
    float*  out     = (float*)d_out;

    k0_convert<<<dim3(HIDx + EMBx + 256), 256, 0, stream>>>(lin0_w, lin1_w, Ws, W0T, W1T, WsT);
    k1_wh  <<<dim3(1024), 256, 0, stream>>>(X, WsT, a, Whb, w1, w2);
    k2_att <<<dim3(Bx * Ex, Nx / 32), 512, 0, stream>>>(edges, Whb, w1, w2, Hb);
    k3_lin0<<<dim3(512), 256, 0, stream>>>(Hb, W0T, lin0_b, h_pre, partials);
    k3b_stats<<<8, 256, 0, stream>>>(partials, gamma, beta, sb);
    k4_lin1<<<dim3(512), 256, 0, stream>>>(h_pre, sb, W1T, lin1_b, out);
}

// Round 8
// 128.741 us; speedup vs baseline: 2.5532x; 1.0139x over previous
//
#include <hip/hip_runtime.h>

#define Bx 32
#define Nx 512
#define Ex 4
#define Fx 128
#define Gx 64
#define HIDx 256
#define EMBx 128
#define NEDGE 8192

typedef __attribute__((ext_vector_type(8))) short bf16x8;
typedef __attribute__((ext_vector_type(4))) float f32x4;

#define L2E 1.44269504f

__device__ __forceinline__ ushort f2bf(float x) {
    unsigned int u = __float_as_uint(x);
    u += 0x7fffu + ((u >> 16) & 1u);
    return (ushort)(u >> 16);
}
__device__ __forceinline__ float bf2f(ushort h) {
    return __uint_as_float(((unsigned int)h) << 16);
}

// ---- K0b: edge binning (blk<128) + weight transpose/cast (blk>=128) --------
// binned[be][...]: per-tile segments of packed (r<<9|d); offs[be][17] bounds.
__global__ __launch_bounds__(512) void k0b(const int* __restrict__ edges,
                                           const float* __restrict__ w0,
                                           const float* __restrict__ w1f,
                                           const float* __restrict__ Wsf,
                                           ushort* __restrict__ W0T,
                                           ushort* __restrict__ W1T,
                                           ushort* __restrict__ WsT,
                                           ushort* __restrict__ binned,
                                           int* __restrict__ offs) {
    __shared__ int hist8[8][16];
    __shared__ int offl[17];
    __shared__ int cur[16];
    int blk = blockIdx.x, tid = threadIdx.x;
    if (blk < 128) {
        int wave = tid >> 6;
        for (int i = tid; i < 128; i += 512) ((int*)hist8)[i] = 0;
        __syncthreads();
        const int4* s4p = (const int4*)(edges + (size_t)blk * 2 * NEDGE);
        const int4* d4p = (const int4*)(edges + (size_t)blk * 2 * NEDGE + NEDGE);
        for (int i = tid; i < NEDGE / 4; i += 512) {
            int4 s4 = s4p[i];
            atomicAdd(&hist8[wave][s4.x >> 5], 1);
            atomicAdd(&hist8[wave][s4.y >> 5], 1);
            atomicAdd(&hist8[wave][s4.z >> 5], 1);
            atomicAdd(&hist8[wave][s4.w >> 5], 1);
        }
        __syncthreads();
        if (tid == 0) {
            int run = 0;
            for (int t = 0; t < 16; ++t) {
                offl[t] = run;
                int s = 0;
                #pragma unroll
                for (int w = 0; w < 8; ++w) s += hist8[w][t];
                run += s;
            }
            offl[16] = run;
            for (int t = 0; t <= 16; ++t) offs[blk * 17 + t] = offl[t];
        }
        __syncthreads();
        if (tid < 16) cur[tid] = offl[tid];
        __syncthreads();
        ushort* bout = binned + (size_t)blk * NEDGE;
        for (int i = tid; i < NEDGE / 4; i += 512) {
            int4 s4 = s4p[i]; int4 d4 = d4p[i];
            int ss[4] = {s4.x, s4.y, s4.z, s4.w};
            int dd[4] = {d4.x, d4.y, d4.z, d4.w};
            #pragma unroll
            for (int u = 0; u < 4; ++u) {
                int t = ss[u] >> 5;
                int pos = atomicAdd(&cur[t], 1);
                bout[pos] = (ushort)(((ss[u] & 31) << 9) | dd[u]);
            }
        }
    } else if (blk < 256) {
        int idx = (blk - 128) * 512 + tid;
        int j = idx >> 8, k = idx & 255;
        W0T[j * HIDx + k] = f2bf(w0[k * HIDx + j]);
    } else if (blk < 320) {
        int idx = (blk - 256) * 512 + tid;
        int j = idx >> 8, k = idx & 255;
        W1T[j * HIDx + k] = f2bf(w1f[k * EMBx + j]);
    } else {
        int idx = (blk - 320) * 512 + tid;
        int eg = idx >> 7, f = idx & 127;
        WsT[eg * Fx + f] = f2bf(Wsf[((eg >> 6) * Fx + f) * Gx + (eg & 63)]);
    }
}

// ---- K1: Whb[be,g,m] = bf16(X @ Ws) via MFMA; w1/w2 = Wh . a ---------------
__global__ __launch_bounds__(256) void k1_wh(const float* __restrict__ X,
                                             const ushort* __restrict__ WsT,
                                             const float* __restrict__ a,
                                             ushort* __restrict__ Whb,
                                             float* __restrict__ w1,
                                             float* __restrict__ w2) {
    __shared__ ushort sXb[64 * 128];   // 16KB, XOR-swizzled bf16 A tile
    int id = blockIdx.x;
    int e = id & 3;
    int rest = id >> 2;
    int tile = rest & 7;
    int b = rest >> 3;
    int be = b * 4 + e;
    int n0 = tile * 64;
    int tid = threadIdx.x;
    for (int i = tid; i < 2048; i += 256) {
        int row = i >> 5, kq = i & 31;
        float4 xv = *(const float4*)&X[(size_t)(b * Nx + n0 + row) * Fx + kq * 4];
        ushort4 hv;
        hv.x = f2bf(xv.x); hv.y = f2bf(xv.y); hv.z = f2bf(xv.z); hv.w = f2bf(xv.w);
        unsigned int byteo = ((unsigned int)(row * 256 + kq * 8)) ^ (((unsigned int)(row & 7)) << 4);
        *(ushort4*)((char*)sXb + byteo) = hv;
    }
    __syncthreads();
    int wave = tid >> 6, lane = tid & 63;
    int arow = lane & 15, kg = lane >> 4;
    int row = wave * 16 + arow;
    f32x4 acc[4];
    #pragma unroll
    for (int t = 0; t < 4; ++t) acc[t] = (f32x4){0.f, 0.f, 0.f, 0.f};
    const ushort* WT = WsT + e * Gx * Fx;   // [g][f]
    unsigned int aswz = ((unsigned int)(row & 7)) << 4;
    #pragma unroll
    for (int ks = 0; ks < 4; ++ks) {
        unsigned int abyte = ((unsigned int)(row * 256 + ks * 64 + kg * 16)) ^ aswz;
        bf16x8 af = *(const bf16x8*)((const char*)sXb + abyte);
        #pragma unroll
        for (int jt = 0; jt < 4; ++jt) {
            bf16x8 bf = *(const bf16x8*)&WT[(size_t)(jt * 16 + arow) * Fx + ks * 32 + kg * 8];
            acc[jt] = __builtin_amdgcn_mfma_f32_16x16x32_bf16(af, bf, acc[jt], 0, 0, 0);
        }
    }
    float a1v[4], a2v[4];
    #pragma unroll
    for (int jt = 0; jt < 4; ++jt) {
        a1v[jt] = a[e * 2 * Gx + jt * 16 + arow];
        a2v[jt] = a[e * 2 * Gx + Gx + jt * 16 + arow];
    }
    int m0 = n0 + wave * 16 + kg * 4;
    #pragma unroll
    for (int jt = 0; jt < 4; ++jt) {
        int g = jt * 16 + arow;
        ushort4 v;
        v.x = f2bf(acc[jt][0]); v.y = f2bf(acc[jt][1]);
        v.z = f2bf(acc[jt][2]); v.w = f2bf(acc[jt][3]);
        *(ushort4*)&Whb[((size_t)be * Gx + g) * Nx + m0] = v;
    }
    #pragma unroll
    for (int reg = 0; reg < 4; ++reg) {
        float p1 = acc[0][reg] * a1v[0] + acc[1][reg] * a1v[1] + acc[2][reg] * a1v[2] + acc[3][reg] * a1v[3];
        float p2 = acc[0][reg] * a2v[0] + acc[1][reg] * a2v[1] + acc[2][reg] * a2v[2] + acc[3][reg] * a2v[3];
        #pragma unroll
        for (int off = 1; off < 16; off <<= 1) {
            p1 += __shfl_xor(p1, off, 64);
            p2 += __shfl_xor(p2, off, 64);
        }
        if (arow == 0) {
            w1[be * Nx + m0 + reg] = p1;
            w2[be * Nx + m0 + reg] = p2;
        }
    }
}

// ---- K2: binned counts -> sparse softmax -> bf16 P -> MFMA PV --------------
__global__ __launch_bounds__(512) void k2_att(const ushort* __restrict__ binned,
                                              const int* __restrict__ offs,
                                              const ushort* __restrict__ Whb,
                                              const float* __restrict__ w1g,
                                              const float* __restrict__ w2g,
                                              ushort* __restrict__ Hb) {
    __shared__ ushort P[32 * 512];          // 32KB; first 16.9KB doubles as cnt
    __shared__ float sw2[512];              // pre-scaled by log2e
    __shared__ float sw1[32];
    __shared__ float sinv[32];
    unsigned int* cnt = (unsigned int*)P;   // [32][132]
    int be = blockIdx.x; int b = be >> 2; int e = be & 3;
    int tile = blockIdx.y; int n0 = tile * 32;
    int tid = threadIdx.x;
    for (int i = tid; i < 32 * 132; i += 512) cnt[i] = 0u;
    sw2[tid] = w2g[be * Nx + tid] * L2E;
    if (tid < 32) sw1[tid] = w1g[be * Nx + n0 + tid] * L2E;
    __syncthreads();
    // phase 2: scatter this tile's binned edges into byte counters
    int t0 = offs[be * 17 + tile], t1 = offs[be * 17 + tile + 1];
    const ushort* bin = binned + (size_t)be * NEDGE;
    for (int i = t0 + tid; i < t1; i += 512) {
        unsigned int pk = bin[i];
        atomicAdd(&cnt[(pk >> 9) * 132 + ((pk & 511u) >> 2)], 1u << ((pk & 3u) * 8));
    }
    __syncthreads();
    // phase 3: sparse softmax — zero own P region, compute nonzeros only
    int r = tid >> 4, c = tid & 15;
    unsigned int cw[8];
    const unsigned int* crow = cnt + r * 132 + c * 8;
    #pragma unroll
    for (int i = 0; i < 8; ++i) cw[i] = crow[i];
    float w1v = sw1[r];
    __syncthreads();   // cnt consumed; P may be overwritten
    unsigned int swz = ((unsigned int)(r & 7)) << 4;
    unsigned int rowb = (unsigned int)(r * 1024);
    #pragma unroll
    for (int tp = 0; tp < 4; ++tp) {
        uint4 z = {0u, 0u, 0u, 0u};
        *(uint4*)((char*)P + ((rowb + (unsigned int)(c * 64 + tp * 16)) ^ swz)) = z;
    }
    float dsum = 0.f; int K = 0;
    #pragma unroll
    for (int t = 0; t < 8; ++t) {
        unsigned int w = cw[t];
        if (!w) continue;
        int dbase = c * 32 + t * 4;
        #pragma unroll
        for (int jj = 0; jj < 4; ++jj) {
            unsigned int ccu = (w >> (jj * 8)) & 255u;
            if (!ccu) continue;
            K++;
            float cf = (float)ccu;
            float ew = __builtin_exp2f(fminf((w1v + sw2[dbase + jj]) * cf, 120.f));
            dsum += ew;
            *(ushort*)((char*)P + ((rowb + (unsigned int)((dbase + jj) * 2)) ^ swz)) = f2bf(ew * cf);
        }
    }
    #pragma unroll
    for (int off = 1; off < 16; off <<= 1) {
        dsum += __shfl_xor(dsum, off, 64);
        K += __shfl_xor(K, off, 64);
    }
    if (c == 0) sinv[r] = 1.f / (dsum + (float)(Nx - K));
    __syncthreads();
    // phase 4: H-tile = P @ Whb (8 waves, one 16x16 sub-tile each)
    int wave = tid >> 6, lane = tid & 63;
    int wr = wave >> 2, wc = wave & 3;
    int row = wr * 16 + (lane & 15);
    int kgrp = lane >> 4;
    f32x4 acc = {0.f, 0.f, 0.f, 0.f};
    const ushort* WB = Whb + (size_t)be * Gx * Nx;
    int g0 = wc * 16 + (lane & 15);
    const ushort* Bp = WB + (size_t)g0 * Nx + kgrp * 8;
    unsigned int aswz = ((unsigned int)(row & 7)) << 4;
    __builtin_amdgcn_s_setprio(1);
    #pragma unroll
    for (int ks = 0; ks < 16; ++ks) {
        unsigned int abyte = ((unsigned int)(row * 1024 + ks * 64 + kgrp * 16)) ^ aswz;
        bf16x8 af = *(const bf16x8*)((const char*)P + abyte);
        bf16x8 bfv = *(const bf16x8*)(Bp + ks * 32);
        acc = __builtin_amdgcn_mfma_f32_16x16x32_bf16(af, bfv, acc, 0, 0, 0);
    }
    __builtin_amdgcn_s_setprio(0);
    float4 iv = *(const float4*)&sinv[wr * 16 + kgrp * 4];
    float ivv[4] = {iv.x, iv.y, iv.z, iv.w};
    #pragma unroll
    for (int reg = 0; reg < 4; ++reg) {
        int rr = n0 + wr * 16 + kgrp * 4 + reg;
        Hb[((size_t)(b * Nx) + rr) * (Ex * Gx) + e * Gx + wc * 16 + (lane & 15)] =
            f2bf(acc[reg] * ivv[reg]);
    }
}

// ---- K3: h_pre = bf16(Hb @ W0 + b) via MFMA; fp32 BN partials --------------
__global__ __launch_bounds__(256) void k3_lin0(const ushort* __restrict__ Hb,
                                               const ushort* __restrict__ W0T,
                                               const float* __restrict__ lin0_b,
                                               ushort* __restrict__ h_pre,
                                               float* __restrict__ partials) {
    __shared__ float red_s[2][256], red_q[2][256];
    int tid = threadIdx.x, wave = tid >> 6, lane = tid & 63;
    int wr = wave >> 1, wc = wave & 1;
    int row0 = blockIdx.x * 32 + wr * 16;
    int arow = lane & 15, kg = lane >> 4;
    const ushort* A = Hb + (size_t)(row0 + arow) * HIDx;
    f32x4 acc[8];
    #pragma unroll
    for (int t = 0; t < 8; ++t) acc[t] = (f32x4){0.f, 0.f, 0.f, 0.f};
    #pragma unroll
    for (int ks = 0; ks < 8; ++ks) {
        int k0 = ks * 32 + kg * 8;
        bf16x8 af = *(const bf16x8*)&A[k0];
        #pragma unroll
        for (int jt = 0; jt < 8; ++jt) {
            bf16x8 bf = *(const bf16x8*)&W0T[(size_t)(wc * 128 + jt * 16 + arow) * HIDx + k0];
            acc[jt] = __builtin_amdgcn_mfma_f32_16x16x32_bf16(af, bf, acc[jt], 0, 0, 0);
        }
    }
    #pragma unroll
    for (int jt = 0; jt < 8; ++jt) {
        int col = wc * 128 + jt * 16 + arow;
        float b = lin0_b[col];
        float s = 0.f, q = 0.f;
        #pragma unroll
        for (int reg = 0; reg < 4; ++reg) {
            float v = acc[jt][reg] + b;
            h_pre[(size_t)(row0 + kg * 4 + reg) * HIDx + col] = f2bf(v);
            s += v; q += v * v;
        }
        s += __shfl_xor(s, 16, 64); s += __shfl_xor(s, 32, 64);
        q += __shfl_xor(q, 16, 64); q += __shfl_xor(q, 32, 64);
        if (lane < 16) { red_s[wr][col] = s; red_q[wr][col] = q; }
    }
    __syncthreads();
    int j = tid;
    partials[(size_t)blockIdx.x * 2 * HIDx + j] = red_s[0][j] + red_s[1][j];
    partials[(size_t)blockIdx.x * 2 * HIDx + HIDx + j] = red_q[0][j] + red_q[1][j];
}

// ---- K3b: finalize BN stats -> scale/bias ----------------------------------
__global__ __launch_bounds__(256) void k3b_stats(const float* __restrict__ partials,
                                                 const float* __restrict__ gamma,
                                                 const float* __restrict__ beta,
                                                 float* __restrict__ sb) {
    __shared__ float rs[8][32], rq[8][32];
    int jl = threadIdx.x & 31, sl = threadIdx.x >> 5;
    int j = blockIdx.x * 32 + jl;
    float s = 0.f, q = 0.f;
    for (int blk = sl; blk < 512; blk += 8) {
        s += partials[blk * 512 + j];
        q += partials[blk * 512 + 256 + j];
    }
    rs[sl][jl] = s; rq[sl][jl] = q;
    __syncthreads();
    if (threadIdx.x < 32) {
        float S = 0.f, Q = 0.f;
        #pragma unroll
        for (int t = 0; t < 8; ++t) { S += rs[t][jl]; Q += rq[t][jl]; }
        const float invM = 1.f / 16384.f;
        float mu = S * invM;
        float var = fmaxf(Q * invM - mu * mu, 0.f);
        float sc = gamma[j] * rsqrtf(var + 1e-5f);
        sb[j] = sc;
        sb[256 + j] = beta[j] - mu * sc;
    }
}

// ---- K4: out = elu(bn(h_pre)) @ W1 + b via MFMA ----------------------------
__global__ __launch_bounds__(256) void k4_lin1(const ushort* __restrict__ h_pre,
                                               const float* __restrict__ sb,
                                               const ushort* __restrict__ W1T,
                                               const float* __restrict__ lin1_b,
                                               float* __restrict__ out) {
    int tid = threadIdx.x, wave = tid >> 6, lane = tid & 63;
    int wr = wave >> 1, wc = wave & 1;
    int row0 = blockIdx.x * 32 + wr * 16;
    int arow = lane & 15, kg = lane >> 4;
    const ushort* A = h_pre + (size_t)(row0 + arow) * HIDx;
    f32x4 acc[4];
    #pragma unroll
    for (int t = 0; t < 4; ++t) acc[t] = (f32x4){0.f, 0.f, 0.f, 0.f};
    #pragma unroll
    for (int ks = 0; ks < 8; ++ks) {
        int k0 = ks * 32 + kg * 8;
        bf16x8 hv = *(const bf16x8*)&A[k0];
        float4 sc0 = *(const float4*)&sb[k0];
        float4 sc1 = *(const float4*)&sb[k0 + 4];
        float4 bi0 = *(const float4*)&sb[256 + k0];
        float4 bi1 = *(const float4*)&sb[256 + k0 + 4];
        float scv[8] = {sc0.x, sc0.y, sc0.z, sc0.w, sc1.x, sc1.y, sc1.z, sc1.w};
        float biv[8] = {bi0.x, bi0.y, bi0.z, bi0.w, bi1.x, bi1.y, bi1.z, bi1.w};
        bf16x8 af;
        #pragma unroll
        for (int u = 0; u < 8; ++u) {
            float v = bf2f((ushort)hv[u]) * scv[u] + biv[u];
            v = v > 0.f ? v : expm1f(v);
            af[u] = (short)f2bf(v);
        }
        #pragma unroll
        for (int jt = 0; jt < 4; ++jt) {
            bf16x8 bf = *(const bf16x8*)&W1T[(size_t)(wc * 64 + jt * 16 + arow) * HIDx + k0];
            acc[jt] = __builtin_amdgcn_mfma_f32_16x16x32_bf16(af, bf, acc[jt], 0, 0, 0);
        }
    }
    #pragma unroll
    for (int jt = 0; jt < 4; ++jt) {
        int col = wc * 64 + jt * 16 + arow;
        float b = lin1_b[col];
        #pragma unroll
        for (int reg = 0; reg < 4; ++reg)
            out[(size_t)(row0 + kg * 4 + reg) * EMBx + col] = acc[jt][reg] + b;
    }
}

extern "C" void kernel_launch(void* const* d_in, const int* in_sizes, int n_in,
                              void* d_out, int out_size, void* d_ws, size_t ws_size,
                              hipStream_t stream) {
    const float* X      = (const float*)d_in[0];
    const int*   edges  = (const int*)d_in[1];
    const float* Ws     = (const float*)d_in[2];
    const float* a      = (const float*)d_in[3];
    const float* lin0_w = (const float*)d_in[4];
    const float* lin0_b = (const float*)d_in[5];
    const float* gamma  = (const float*)d_in[6];
    const float* beta   = (const float*)d_in[7];
    const float* lin1_w = (const float*)d_in[8];
    const float* lin1_b = (const float*)d_in[9];
    float* ws = (float*)d_ws;

    // region0 (floats 0..4194303): Whb bf16 [floats 0..2097151] (k1,k2) then
    // h_pre bf16 (k3,k4); binned [floats 2097152..2621439] (k0b->k2);
    // offs [floats 2621440..] — all disjoint in time/space.
    ushort* Whb     = (ushort*)ws;
    ushort* h_pre   = (ushort*)ws;
    ushort* binned  = (ushort*)ws + 4194304;
    int*    offs    = (int*)(ws + 2621440);
    ushort* Hb      = (ushort*)(ws + 4194304);
    float*  w1      = ws + 8388608;              // 65,536
    float*  w2      = ws + 8454144;              // 65,536
    float*  partials= ws + 8519680;              // 262,144
    float*  sb      = ws + 8781824;              // 512
    ushort* WsT     = (ushort*)(ws + 8782336);   // 32,768 ushorts
    ushort* W0T     = (ushort*)(ws + 8798720);   // 65,536 ushorts
    ushort* W1T     = (ushort*)(ws + 8831488);   // 32,768 ushorts
    float*  out     = (float*)d_out;

    k0b    <<<dim3(384), 512, 0, stream>>>(edges, lin0_w, lin1_w, Ws, W0T, W1T, WsT, binned, offs);
    k1_wh  <<<dim3(1024), 256, 0, stream>>>(X, WsT, a, Whb, w1, w2);
    k2_att <<<dim3(Bx * Ex, Nx / 32), 512, 0, stream>>>(binned, offs, Whb, w1, w2, Hb);
    k3_lin0<<<dim3(512), 256, 0, stream>>>(Hb, W0T, lin0_b, h_pre, partials);
    k3b_stats<<<8, 256, 0, stream>>>(partials, gamma, beta, sb);
    k4_lin1<<<dim3(512), 256, 0, stream>>>(h_pre, sb, W1T, lin1_b, out);
}

// Round 9
// 128.312 us; speedup vs baseline: 2.5617x; 1.0033x over previous
//
#include <hip/hip_runtime.h>

#define Bx 32
#define Nx 512
#define Ex 4
#define Fx 128
#define Gx 64
#define HIDx 256
#define EMBx 128
#define NEDGE 8192

typedef __attribute__((ext_vector_type(8))) short bf16x8;
typedef __attribute__((ext_vector_type(4))) float f32x4;

#define L2E 1.44269504f

__device__ __forceinline__ ushort f2bf(float x) {
    unsigned int u = __float_as_uint(x);
    u += 0x7fffu + ((u >> 16) & 1u);
    return (ushort)(u >> 16);
}
__device__ __forceinline__ float bf2f(ushort h) {
    return __uint_as_float(((unsigned int)h) << 16);
}

// ---- K0b: edge binning (blk<128) + weight transpose/cast (blk>=128) --------
__global__ __launch_bounds__(512) void k0b(const int* __restrict__ edges,
                                           const float* __restrict__ w0,
                                           const float* __restrict__ w1f,
                                           const float* __restrict__ Wsf,
                                           ushort* __restrict__ W0T,
                                           ushort* __restrict__ W1T,
                                           ushort* __restrict__ WsT,
                                           ushort* __restrict__ binned,
                                           int* __restrict__ offs) {
    __shared__ int hist8[8][16];
    __shared__ int offl[17];
    __shared__ int cur[16];
    int blk = blockIdx.x, tid = threadIdx.x;
    if (blk < 128) {
        int wave = tid >> 6;
        for (int i = tid; i < 128; i += 512) ((int*)hist8)[i] = 0;
        __syncthreads();
        const int4* s4p = (const int4*)(edges + (size_t)blk * 2 * NEDGE);
        const int4* d4p = (const int4*)(edges + (size_t)blk * 2 * NEDGE + NEDGE);
        for (int i = tid; i < NEDGE / 4; i += 512) {
            int4 s4 = s4p[i];
            atomicAdd(&hist8[wave][s4.x >> 5], 1);
            atomicAdd(&hist8[wave][s4.y >> 5], 1);
            atomicAdd(&hist8[wave][s4.z >> 5], 1);
            atomicAdd(&hist8[wave][s4.w >> 5], 1);
        }
        __syncthreads();
        if (tid == 0) {
            int run = 0;
            for (int t = 0; t < 16; ++t) {
                offl[t] = run;
                int s = 0;
                #pragma unroll
                for (int w = 0; w < 8; ++w) s += hist8[w][t];
                run += s;
            }
            offl[16] = run;
            for (int t = 0; t <= 16; ++t) offs[blk * 17 + t] = offl[t];
        }
        __syncthreads();
        if (tid < 16) cur[tid] = offl[tid];
        __syncthreads();
        ushort* bout = binned + (size_t)blk * NEDGE;
        for (int i = tid; i < NEDGE / 4; i += 512) {
            int4 s4 = s4p[i]; int4 d4 = d4p[i];
            int ss[4] = {s4.x, s4.y, s4.z, s4.w};
            int dd[4] = {d4.x, d4.y, d4.z, d4.w};
            #pragma unroll
            for (int u = 0; u < 4; ++u) {
                int t = ss[u] >> 5;
                int pos = atomicAdd(&cur[t], 1);
                bout[pos] = (ushort)(((ss[u] & 31) << 9) | dd[u]);
            }
        }
    } else if (blk < 256) {
        int idx = (blk - 128) * 512 + tid;
        int j = idx >> 8, k = idx & 255;
        W0T[j * HIDx + k] = f2bf(w0[k * HIDx + j]);
    } else if (blk < 320) {
        int idx = (blk - 256) * 512 + tid;
        int j = idx >> 8, k = idx & 255;
        W1T[j * HIDx + k] = f2bf(w1f[k * EMBx + j]);
    } else {
        int idx = (blk - 320) * 512 + tid;
        int eg = idx >> 7, f = idx & 127;
        WsT[eg * Fx + f] = f2bf(Wsf[((eg >> 6) * Fx + f) * Gx + (eg & 63)]);
    }
}

// ---- K1: Whb[be,g,m] = bf16(X @ Ws) via MFMA; w1/w2 = Wh . a ---------------
__global__ __launch_bounds__(256) void k1_wh(const float* __restrict__ X,
                                             const ushort* __restrict__ WsT,
                                             const float* __restrict__ a,
                                             ushort* __restrict__ Whb,
                                             float* __restrict__ w1,
                                             float* __restrict__ w2) {
    __shared__ ushort sXb[64 * 128];   // 16KB, XOR-swizzled bf16 A tile
    int id = blockIdx.x;
    int e = id & 3;
    int rest = id >> 2;
    int tile = rest & 7;
    int b = rest >> 3;
    int be = b * 4 + e;
    int n0 = tile * 64;
    int tid = threadIdx.x;
    for (int i = tid; i < 2048; i += 256) {
        int row = i >> 5, kq = i & 31;
        float4 xv = *(const float4*)&X[(size_t)(b * Nx + n0 + row) * Fx + kq * 4];
        ushort4 hv;
        hv.x = f2bf(xv.x); hv.y = f2bf(xv.y); hv.z = f2bf(xv.z); hv.w = f2bf(xv.w);
        unsigned int byteo = ((unsigned int)(row * 256 + kq * 8)) ^ (((unsigned int)(row & 7)) << 4);
        *(ushort4*)((char*)sXb + byteo) = hv;
    }
    __syncthreads();
    int wave = tid >> 6, lane = tid & 63;
    int arow = lane & 15, kg = lane >> 4;
    int row = wave * 16 + arow;
    f32x4 acc[4];
    #pragma unroll
    for (int t = 0; t < 4; ++t) acc[t] = (f32x4){0.f, 0.f, 0.f, 0.f};
    const ushort* WT = WsT + e * Gx * Fx;   // [g][f]
    unsigned int aswz = ((unsigned int)(row & 7)) << 4;
    #pragma unroll
    for (int ks = 0; ks < 4; ++ks) {
        unsigned int abyte = ((unsigned int)(row * 256 + ks * 64 + kg * 16)) ^ aswz;
        bf16x8 af = *(const bf16x8*)((const char*)sXb + abyte);
        #pragma unroll
        for (int jt = 0; jt < 4; ++jt) {
            bf16x8 bf = *(const bf16x8*)&WT[(size_t)(jt * 16 + arow) * Fx + ks * 32 + kg * 8];
            acc[jt] = __builtin_amdgcn_mfma_f32_16x16x32_bf16(af, bf, acc[jt], 0, 0, 0);
        }
    }
    float a1v[4], a2v[4];
    #pragma unroll
    for (int jt = 0; jt < 4; ++jt) {
        a1v[jt] = a[e * 2 * Gx + jt * 16 + arow];
        a2v[jt] = a[e * 2 * Gx + Gx + jt * 16 + arow];
    }
    int m0 = n0 + wave * 16 + kg * 4;
    #pragma unroll
    for (int jt = 0; jt < 4; ++jt) {
        int g = jt * 16 + arow;
        ushort4 v;
        v.x = f2bf(acc[jt][0]); v.y = f2bf(acc[jt][1]);
        v.z = f2bf(acc[jt][2]); v.w = f2bf(acc[jt][3]);
        *(ushort4*)&Whb[((size_t)be * Gx + g) * Nx + m0] = v;
    }
    #pragma unroll
    for (int reg = 0; reg < 4; ++reg) {
        float p1 = acc[0][reg] * a1v[0] + acc[1][reg] * a1v[1] + acc[2][reg] * a1v[2] + acc[3][reg] * a1v[3];
        float p2 = acc[0][reg] * a2v[0] + acc[1][reg] * a2v[1] + acc[2][reg] * a2v[2] + acc[3][reg] * a2v[3];
        #pragma unroll
        for (int off = 1; off < 16; off <<= 1) {
            p1 += __shfl_xor(p1, off, 64);
            p2 += __shfl_xor(p2, off, 64);
        }
        if (arow == 0) {
            w1[be * Nx + m0 + reg] = p1;
            w2[be * Nx + m0 + reg] = p2;
        }
    }
}

// ---- K2: binned edges -> owner-compacted softmax -> bf16 P -> MFMA PV ------
__global__ __launch_bounds__(512) void k2_att(const ushort* __restrict__ binned,
                                              const int* __restrict__ offs,
                                              const ushort* __restrict__ Whb,
                                              const float* __restrict__ w1g,
                                              const float* __restrict__ w2g,
                                              ushort* __restrict__ Hb) {
    __shared__ ushort P[32 * 512];          // 32KB; first 16.9KB doubles as cnt
    __shared__ float sw2[512];              // pre-scaled by log2e
    __shared__ float sw1[32];
    __shared__ float sinv[32];
    __shared__ float rowsum[32];
    __shared__ int   rowK[32];
    __shared__ ushort olist[2048];          // compacted distinct (r<<9|d)
    __shared__ int ocnt;
    unsigned int* cnt = (unsigned int*)P;   // [32][132]
    int be = blockIdx.x; int b = be >> 2; int e = be & 3;
    int tile = blockIdx.y; int n0 = tile * 32;
    int tid = threadIdx.x;
    for (int i = tid; i < 32 * 132; i += 512) cnt[i] = 0u;
    sw2[tid] = w2g[be * Nx + tid] * L2E;
    if (tid < 32) {
        sw1[tid] = w1g[be * Nx + n0 + tid] * L2E;
        rowsum[tid] = 0.f; rowK[tid] = 0;
    }
    if (tid == 0) ocnt = 0;
    __syncthreads();
    // phase 2: scatter binned edges into byte counters; old-byte==0 => owner
    int t0 = offs[be * 17 + tile], t1 = offs[be * 17 + tile + 1];
    const ushort* bin = binned + (size_t)be * NEDGE;
    for (int i = t0 + tid; i < t1; i += 512) {
        unsigned int pk = bin[i];
        unsigned int sh = (pk & 3u) * 8;
        unsigned int old = atomicAdd(&cnt[(pk >> 9) * 132 + ((pk & 511u) >> 2)], 1u << sh);
        if (((old >> sh) & 255u) == 0u) {
            int ix = atomicAdd(&ocnt, 1);
            if (ix < 2048) olist[ix] = (ushort)pk;
        }
    }
    __syncthreads();
    // phase 3a: process owned entries (<=4/thread, static regs)
    int tot = ocnt; if (tot > 2048) tot = 2048;
    const unsigned char* cb = (const unsigned char*)cnt;
    ushort pbv[4]; int pkv[4];
    #pragma unroll
    for (int u = 0; u < 4; ++u) {
        int i = tid + u * 512;
        bool v = i < tot;
        int pk = v ? (int)olist[i] : 0;
        int r = pk >> 9, d = pk & 511;
        float c = (float)cb[r * 528 + d];
        float ew = __builtin_exp2f(fminf((sw1[r] + sw2[d]) * c, 120.f));
        if (v) {
            atomicAdd(&rowsum[r], ew);
            atomicAdd(&rowK[r], 1);
        }
        pbv[u] = f2bf(ew * c);
        pkv[u] = v ? pk : -1;
    }
    __syncthreads();   // cnt fully consumed; P may be overwritten
    // phase 3b: zero P
    {
        uint4 z = {0u, 0u, 0u, 0u};
        #pragma unroll
        for (int u = 0; u < 4; ++u)
            *(uint4*)((char*)P + tid * 64 + u * 16) = z;
    }
    __syncthreads();
    // phase 3c: scatter bf16 weights (unique (r,d) -> race-free); sinv
    #pragma unroll
    for (int u = 0; u < 4; ++u) {
        if (pkv[u] >= 0) {
            int r = pkv[u] >> 9, d = pkv[u] & 511;
            unsigned int byteo = ((unsigned int)(r * 1024 + d * 2)) ^ (((unsigned int)(r & 7)) << 4);
            *(ushort*)((char*)P + byteo) = pbv[u];
        }
    }
    if (tid < 32) sinv[tid] = 1.f / (rowsum[tid] + (float)(Nx - rowK[tid]));
    __syncthreads();
    // phase 4: H-tile = P @ Whb (8 waves, one 16x16 sub-tile each)
    int wave = tid >> 6, lane = tid & 63;
    int wr = wave >> 2, wc = wave & 3;
    int row = wr * 16 + (lane & 15);
    int kgrp = lane >> 4;
    f32x4 acc = {0.f, 0.f, 0.f, 0.f};
    const ushort* WB = Whb + (size_t)be * Gx * Nx;
    int g0 = wc * 16 + (lane & 15);
    const ushort* Bp = WB + (size_t)g0 * Nx + kgrp * 8;
    unsigned int aswz = ((unsigned int)(row & 7)) << 4;
    __builtin_amdgcn_s_setprio(1);
    #pragma unroll
    for (int ks = 0; ks < 16; ++ks) {
        unsigned int abyte = ((unsigned int)(row * 1024 + ks * 64 + kgrp * 16)) ^ aswz;
        bf16x8 af = *(const bf16x8*)((const char*)P + abyte);
        bf16x8 bfv = *(const bf16x8*)(Bp + ks * 32);
        acc = __builtin_amdgcn_mfma_f32_16x16x32_bf16(af, bfv, acc, 0, 0, 0);
    }
    __builtin_amdgcn_s_setprio(0);
    float4 iv = *(const float4*)&sinv[wr * 16 + kgrp * 4];
    float ivv[4] = {iv.x, iv.y, iv.z, iv.w};
    #pragma unroll
    for (int reg = 0; reg < 4; ++reg) {
        int rr = n0 + wr * 16 + kgrp * 4 + reg;
        Hb[((size_t)(b * Nx) + rr) * (Ex * Gx) + e * Gx + wc * 16 + (lane & 15)] =
            f2bf(acc[reg] * ivv[reg]);
    }
}

// ---- K3: h_pre = bf16(Hb @ W0 + b) via MFMA; fp32 BN partials --------------
__global__ __launch_bounds__(256) void k3_lin0(const ushort* __restrict__ Hb,
                                               const ushort* __restrict__ W0T,
                                               const float* __restrict__ lin0_b,
                                               ushort* __restrict__ h_pre,
                                               float* __restrict__ partials) {
    __shared__ float red_s[2][256], red_q[2][256];
    int tid = threadIdx.x, wave = tid >> 6, lane = tid & 63;
    int wr = wave >> 1, wc = wave & 1;
    int row0 = blockIdx.x * 32 + wr * 16;
    int arow = lane & 15, kg = lane >> 4;
    const ushort* A = Hb + (size_t)(row0 + arow) * HIDx;
    f32x4 acc[8];
    #pragma unroll
    for (int t = 0; t < 8; ++t) acc[t] = (f32x4){0.f, 0.f, 0.f, 0.f};
    #pragma unroll
    for (int ks = 0; ks < 8; ++ks) {
        int k0 = ks * 32 + kg * 8;
        bf16x8 af = *(const bf16x8*)&A[k0];
        #pragma unroll
        for (int jt = 0; jt < 8; ++jt) {
            bf16x8 bf = *(const bf16x8*)&W0T[(size_t)(wc * 128 + jt * 16 + arow) * HIDx + k0];
            acc[jt] = __builtin_amdgcn_mfma_f32_16x16x32_bf16(af, bf, acc[jt], 0, 0, 0);
        }
    }
    #pragma unroll
    for (int jt = 0; jt < 8; ++jt) {
        int col = wc * 128 + jt * 16 + arow;
        float b = lin0_b[col];
        float s = 0.f, q = 0.f;
        #pragma unroll
        for (int reg = 0; reg < 4; ++reg) {
            float v = acc[jt][reg] + b;
            h_pre[(size_t)(row0 + kg * 4 + reg) * HIDx + col] = f2bf(v);
            s += v; q += v * v;
        }
        s += __shfl_xor(s, 16, 64); s += __shfl_xor(s, 32, 64);
        q += __shfl_xor(q, 16, 64); q += __shfl_xor(q, 32, 64);
        if (lane < 16) { red_s[wr][col] = s; red_q[wr][col] = q; }
    }
    __syncthreads();
    int j = tid;
    partials[(size_t)blockIdx.x * 2 * HIDx + j] = red_s[0][j] + red_s[1][j];
    partials[(size_t)blockIdx.x * 2 * HIDx + HIDx + j] = red_q[0][j] + red_q[1][j];
}

// ---- K3b: finalize BN stats -> scale/bias ----------------------------------
__global__ __launch_bounds__(256) void k3b_stats(const float* __restrict__ partials,
                                                 const float* __restrict__ gamma,
                                                 const float* __restrict__ beta,
                                                 float* __restrict__ sb) {
    __shared__ float rs[8][32], rq[8][32];
    int jl = threadIdx.x & 31, sl = threadIdx.x >> 5;
    int j = blockIdx.x * 32 + jl;
    float s = 0.f, q = 0.f;
    for (int blk = sl; blk < 512; blk += 8) {
        s += partials[blk * 512 + j];
        q += partials[blk * 512 + 256 + j];
    }
    rs[sl][jl] = s; rq[sl][jl] = q;
    __syncthreads();
    if (threadIdx.x < 32) {
        float S = 0.f, Q = 0.f;
        #pragma unroll
        for (int t = 0; t < 8; ++t) { S += rs[t][jl]; Q += rq[t][jl]; }
        const float invM = 1.f / 16384.f;
        float mu = S * invM;
        float var = fmaxf(Q * invM - mu * mu, 0.f);
        float sc = gamma[j] * rsqrtf(var + 1e-5f);
        sb[j] = sc;
        sb[256 + j] = beta[j] - mu * sc;
    }
}

// ---- K4: out = elu(bn(h_pre)) @ W1 + b via MFMA ----------------------------
__global__ __launch_bounds__(256) void k4_lin1(const ushort* __restrict__ h_pre,
                                               const float* __restrict__ sb,
                                               const ushort* __restrict__ W1T,
                                               const float* __restrict__ lin1_b,
                                               float* __restrict__ out) {
    int tid = threadIdx.x, wave = tid >> 6, lane = tid & 63;
    int wr = wave >> 1, wc = wave & 1;
    int row0 = blockIdx.x * 32 + wr * 16;
    int arow = lane & 15, kg = lane >> 4;
    const ushort* A = h_pre + (size_t)(row0 + arow) * HIDx;
    f32x4 acc[4];
    #pragma unroll
    for (int t = 0; t < 4; ++t) acc[t] = (f32x4){0.f, 0.f, 0.f, 0.f};
    #pragma unroll
    for (int ks = 0; ks < 8; ++ks) {
        int k0 = ks * 32 + kg * 8;
        bf16x8 hv = *(const bf16x8*)&A[k0];
        float4 sc0 = *(const float4*)&sb[k0];
        float4 sc1 = *(const float4*)&sb[k0 + 4];
        float4 bi0 = *(const float4*)&sb[256 + k0];
        float4 bi1 = *(const float4*)&sb[256 + k0 + 4];
        float scv[8] = {sc0.x, sc0.y, sc0.z, sc0.w, sc1.x, sc1.y, sc1.z, sc1.w};
        float biv[8] = {bi0.x, bi0.y, bi0.z, bi0.w, bi1.x, bi1.y, bi1.z, bi1.w};
        bf16x8 af;
        #pragma unroll
        for (int u = 0; u < 8; ++u) {
            float v = bf2f((ushort)hv[u]) * scv[u] + biv[u];
            v = v > 0.f ? v : expm1f(v);
            af[u] = (short)f2bf(v);
        }
        #pragma unroll
        for (int jt = 0; jt < 4; ++jt) {
            bf16x8 bf = *(const bf16x8*)&W1T[(size_t)(wc * 64 + jt * 16 + arow) * HIDx + k0];
            acc[jt] = __builtin_amdgcn_mfma_f32_16x16x32_bf16(af, bf, acc[jt], 0, 0, 0);
        }
    }
    #pragma unroll
    for (int jt = 0; jt < 4; ++jt) {
        int col = wc * 64 + jt * 16 + arow;
        float b = lin1_b[col];
        #pragma unroll
        for (int reg = 0; reg < 4; ++reg)
            out[(size_t)(row0 + kg * 4 + reg) * EMBx + col] = acc[jt][reg] + b;
    }
}

extern "C" void kernel_launch(void* const* d_in, const int* in_sizes, int n_in,
                              void* d_out, int out_size, void* d_ws, size_t ws_size,
                              hipStream_t stream) {
    const float* X      = (const float*)d_in[0];
    const int*   edges  = (const int*)d_in[1];
    const float* Ws     = (const float*)d_in[2];
    const float* a      = (const float*)d_in[3];
    const float* lin0_w = (const float*)d_in[4];
    const float* lin0_b = (const float*)d_in[5];
    const float* gamma  = (const float*)d_in[6];
    const float* beta   = (const float*)d_in[7];
    const float* lin1_w = (const float*)d_in[8];
    const float* lin1_b = (const float*)d_in[9];
    float* ws = (float*)d_ws;

    ushort* Whb     = (ushort*)ws;
    ushort* h_pre   = (ushort*)ws;
    ushort* binned  = (ushort*)ws + 4194304;
    int*    offs    = (int*)(ws + 2621440);
    ushort* Hb      = (ushort*)(ws + 4194304);
    float*  w1      = ws + 8388608;              // 65,536
    float*  w2      = ws + 8454144;              // 65,536
    float*  partials= ws + 8519680;              // 262,144
    float*  sb      = ws + 8781824;              // 512
    ushort* WsT     = (ushort*)(ws + 8782336);   // 32,768 ushorts
    ushort* W0T     = (ushort*)(ws + 8798720);   // 65,536 ushorts
    ushort* W1T     = (ushort*)(ws + 8831488);   // 32,768 ushorts
    float*  out     = (float*)d_out;

    k0b    <<<dim3(384), 512, 0, stream>>>(edges, lin0_w, lin1_w, Ws, W0T, W1T, WsT, binned, offs);
    k1_wh  <<<dim3(1024), 256, 0, stream>>>(X, WsT, a, Whb, w1, w2);
    k2_att <<<dim3(Bx * Ex, Nx / 32), 512, 0, stream>>>(binned, offs, Whb, w1, w2, Hb);
    k3_lin0<<<dim3(512), 256, 0, stream>>>(Hb, W0T, lin0_b, h_pre, partials);
    k3b_stats<<<8, 256, 0, stream>>>(partials, gamma, beta, sb);
    k4_lin1<<<dim3(512), 256, 0, stream>>>(h_pre, sb, W1T, lin1_b, out);
}

// Round 11
// 120.882 us; speedup vs baseline: 2.7192x; 1.0615x over previous
//
#include <hip/hip_runtime.h>

#define Bx 32
#define Nx 512
#define Ex 4
#define Fx 128
#define Gx 64
#define HIDx 256
#define EMBx 128
#define NEDGE 8192

typedef __attribute__((ext_vector_type(8))) short bf16x8;
typedef __attribute__((ext_vector_type(4))) float f32x4;

#define L2E 1.44269504f

__device__ __forceinline__ ushort f2bf(float x) {
    unsigned int u = __float_as_uint(x);
    u += 0x7fffu + ((u >> 16) & 1u);
    return (ushort)(u >> 16);
}
__device__ __forceinline__ float bf2f(ushort h) {
    return __uint_as_float(((unsigned int)h) << 16);
}

// ---- K0b: edge binning into 8 x 64-row segments + weight transpose/cast ----
__global__ __launch_bounds__(512) void k0b(const int* __restrict__ edges,
                                           const float* __restrict__ w0,
                                           const float* __restrict__ w1f,
                                           const float* __restrict__ Wsf,
                                           ushort* __restrict__ W0T,
                                           ushort* __restrict__ W1T,
                                           ushort* __restrict__ WsT,
                                           ushort* __restrict__ binned,
                                           int* __restrict__ offs) {
    __shared__ int hist8[8][8];
    __shared__ int offl[9];
    __shared__ int cur[8];
    int blk = blockIdx.x, tid = threadIdx.x;
    if (blk < 128) {
        int wave = tid >> 6;
        if (tid < 64) ((int*)hist8)[tid] = 0;
        __syncthreads();
        const int4* s4p = (const int4*)(edges + (size_t)blk * 2 * NEDGE);
        const int4* d4p = (const int4*)(edges + (size_t)blk * 2 * NEDGE + NEDGE);
        for (int i = tid; i < NEDGE / 4; i += 512) {
            int4 s4 = s4p[i];
            atomicAdd(&hist8[wave][s4.x >> 6], 1);
            atomicAdd(&hist8[wave][s4.y >> 6], 1);
            atomicAdd(&hist8[wave][s4.z >> 6], 1);
            atomicAdd(&hist8[wave][s4.w >> 6], 1);
        }
        __syncthreads();
        if (tid == 0) {
            int run = 0;
            for (int t = 0; t < 8; ++t) {
                offl[t] = run;
                int s = 0;
                #pragma unroll
                for (int w = 0; w < 8; ++w) s += hist8[w][t];
                run += s;
            }
            offl[8] = run;
            for (int t = 0; t <= 8; ++t) offs[blk * 9 + t] = offl[t];
        }
        __syncthreads();
        if (tid < 8) cur[tid] = offl[tid];
        __syncthreads();
        ushort* bout = binned + (size_t)blk * NEDGE;
        for (int i = tid; i < NEDGE / 4; i += 512) {
            int4 s4 = s4p[i]; int4 d4 = d4p[i];
            int ss[4] = {s4.x, s4.y, s4.z, s4.w};
            int dd[4] = {d4.x, d4.y, d4.z, d4.w};
            #pragma unroll
            for (int u = 0; u < 4; ++u) {
                int t = ss[u] >> 6;
                int pos = atomicAdd(&cur[t], 1);
                bout[pos] = (ushort)(((ss[u] & 63) << 9) | dd[u]);
            }
        }
    } else if (blk < 256) {
        int idx = (blk - 128) * 512 + tid;
        int j = idx >> 8, k = idx & 255;
        W0T[j * HIDx + k] = f2bf(w0[k * HIDx + j]);
    } else if (blk < 320) {
        int idx = (blk - 256) * 512 + tid;
        int j = idx >> 8, k = idx & 255;
        W1T[j * HIDx + k] = f2bf(w1f[k * EMBx + j]);
    } else {
        int idx = (blk - 320) * 512 + tid;
        int eg = idx >> 7, f = idx & 127;
        WsT[eg * Fx + f] = f2bf(Wsf[((eg >> 6) * Fx + f) * Gx + (eg & 63)]);
    }
}

// ---- K1: Whb[be,g,m] = bf16(X @ Ws) via MFMA; w1/w2 = Wh . a ---------------
__global__ __launch_bounds__(256) void k1_wh(const float* __restrict__ X,
                                             const ushort* __restrict__ WsT,
                                             const float* __restrict__ a,
                                             ushort* __restrict__ Whb,
                                             float* __restrict__ w1,
                                             float* __restrict__ w2) {
    __shared__ ushort sXb[64 * 128];   // 16KB, XOR-swizzled bf16 A tile
    int id = blockIdx.x;
    int e = id & 3;
    int rest = id >> 2;
    int tile = rest & 7;
    int b = rest >> 3;
    int be = b * 4 + e;
    int n0 = tile * 64;
    int tid = threadIdx.x;
    for (int i = tid; i < 2048; i += 256) {
        int row = i >> 5, kq = i & 31;
        float4 xv = *(const float4*)&X[(size_t)(b * Nx + n0 + row) * Fx + kq * 4];
        ushort4 hv;
        hv.x = f2bf(xv.x); hv.y = f2bf(xv.y); hv.z = f2bf(xv.z); hv.w = f2bf(xv.w);
        unsigned int byteo = ((unsigned int)(row * 256 + kq * 8)) ^ (((unsigned int)(row & 7)) << 4);
        *(ushort4*)((char*)sXb + byteo) = hv;
    }
    __syncthreads();
    int wave = tid >> 6, lane = tid & 63;
    int arow = lane & 15, kg = lane >> 4;
    int row = wave * 16 + arow;
    f32x4 acc[4];
    #pragma unroll
    for (int t = 0; t < 4; ++t) acc[t] = (f32x4){0.f, 0.f, 0.f, 0.f};
    const ushort* WT = WsT + e * Gx * Fx;   // [g][f]
    unsigned int aswz = ((unsigned int)(row & 7)) << 4;
    #pragma unroll
    for (int ks = 0; ks < 4; ++ks) {
        unsigned int abyte = ((unsigned int)(row * 256 + ks * 64 + kg * 16)) ^ aswz;
        bf16x8 af = *(const bf16x8*)((const char*)sXb + abyte);
        #pragma unroll
        for (int jt = 0; jt < 4; ++jt) {
            bf16x8 bf = *(const bf16x8*)&WT[(size_t)(jt * 16 + arow) * Fx + ks * 32 + kg * 8];
            acc[jt] = __builtin_amdgcn_mfma_f32_16x16x32_bf16(af, bf, acc[jt], 0, 0, 0);
        }
    }
    float a1v[4], a2v[4];
    #pragma unroll
    for (int jt = 0; jt < 4; ++jt) {
        a1v[jt] = a[e * 2 * Gx + jt * 16 + arow];
        a2v[jt] = a[e * 2 * Gx + Gx + jt * 16 + arow];
    }
    int m0 = n0 + wave * 16 + kg * 4;
    #pragma unroll
    for (int jt = 0; jt < 4; ++jt) {
        int g = jt * 16 + arow;
        ushort4 v;
        v.x = f2bf(acc[jt][0]); v.y = f2bf(acc[jt][1]);
        v.z = f2bf(acc[jt][2]); v.w = f2bf(acc[jt][3]);
        *(ushort4*)&Whb[((size_t)be * Gx + g) * Nx + m0] = v;
    }
    #pragma unroll
    for (int reg = 0; reg < 4; ++reg) {
        float p1 = acc[0][reg] * a1v[0] + acc[1][reg] * a1v[1] + acc[2][reg] * a1v[2] + acc[3][reg] * a1v[3];
        float p2 = acc[0][reg] * a2v[0] + acc[1][reg] * a2v[1] + acc[2][reg] * a2v[2] + acc[3][reg] * a2v[3];
        #pragma unroll
        for (int off = 1; off < 16; off <<= 1) {
            p1 += __shfl_xor(p1, off, 64);
            p2 += __shfl_xor(p2, off, 64);
        }
        if (arow == 0) {
            w1[be * Nx + m0 + reg] = p1;
            w2[be * Nx + m0 + reg] = p2;
        }
    }
}

// ---- K2: 64-row tiles; binned edges -> owner-compacted softmax -> MFMA PV --
__global__ __launch_bounds__(512) void k2_att(const ushort* __restrict__ binned,
                                              const int* __restrict__ offs,
                                              const ushort* __restrict__ Whb,
                                              const float* __restrict__ w1g,
                                              const float* __restrict__ w2g,
                                              ushort* __restrict__ Hb) {
    __shared__ ushort P[64 * 512];          // 64KB; first 33.8KB doubles as cnt
    __shared__ float sw2[512];              // pre-scaled by log2e
    __shared__ float sw1[64];
    __shared__ float sinv[64];
    __shared__ float rowsum[64];
    __shared__ int   rowK[64];
    __shared__ ushort olist[4096];          // compacted distinct (r<<9|d)
    __shared__ int ocnt;
    unsigned int* cnt = (unsigned int*)P;   // [64][132]
    int be = blockIdx.x; int b = be >> 2; int e = be & 3;
    int tile = blockIdx.y; int n0 = tile * 64;
    int tid = threadIdx.x;
    for (int i = tid; i < 64 * 132; i += 512) cnt[i] = 0u;
    sw2[tid] = w2g[be * Nx + tid] * L2E;
    if (tid < 64) {
        sw1[tid] = w1g[be * Nx + n0 + tid] * L2E;
        rowsum[tid] = 0.f; rowK[tid] = 0;
    }
    if (tid == 0) ocnt = 0;
    __syncthreads();
    // phase 2: scatter binned edges into byte counters; old-byte==0 => owner
    int t0 = offs[be * 9 + tile], t1 = offs[be * 9 + tile + 1];
    const ushort* bin = binned + (size_t)be * NEDGE;
    for (int i = t0 + tid; i < t1; i += 512) {
        unsigned int pk = bin[i];
        unsigned int sh = (pk & 3u) * 8;
        unsigned int old = atomicAdd(&cnt[(pk >> 9) * 132 + ((pk & 511u) >> 2)], 1u << sh);
        if (((old >> sh) & 255u) == 0u) {
            int ix = atomicAdd(&ocnt, 1);
            if (ix < 4096) olist[ix] = (ushort)pk;
        }
    }
    __syncthreads();
    // phase 3a: process owned entries (<=8/thread, static regs)
    int tot = ocnt; if (tot > 4096) tot = 4096;
    const unsigned char* cb = (const unsigned char*)cnt;
    ushort pbv[8]; int pkv[8];
    #pragma unroll
    for (int u = 0; u < 8; ++u) {
        int i = tid + u * 512;
        bool v = i < tot;
        int pk = v ? (int)olist[i] : 0;
        int r = pk >> 9, d = pk & 511;
        float c = (float)cb[r * 528 + d];
        float ew = __builtin_exp2f(fminf((sw1[r] + sw2[d]) * c, 120.f));
        if (v) {
            atomicAdd(&rowsum[r], ew);
            atomicAdd(&rowK[r], 1);
        }
        pbv[u] = f2bf(ew * c);
        pkv[u] = v ? pk : -1;
    }
    __syncthreads();   // cnt fully consumed; P may be overwritten
    // phase 3b: zero P (128B per thread)
    {
        uint4 z = {0u, 0u, 0u, 0u};
        #pragma unroll
        for (int u = 0; u < 8; ++u)
            *(uint4*)((char*)P + tid * 128 + u * 16) = z;
    }
    __syncthreads();
    // phase 3c: scatter bf16 weights (unique (r,d) -> race-free); sinv
    #pragma unroll
    for (int u = 0; u < 8; ++u) {
        if (pkv[u] >= 0) {
            int r = pkv[u] >> 9, d = pkv[u] & 511;
            unsigned int byteo = ((unsigned int)(r * 1024 + d * 2)) ^ (((unsigned int)(r & 7)) << 4);
            *(ushort*)((char*)P + byteo) = pbv[u];
        }
    }
    if (tid < 64) sinv[tid] = 1.f / (rowsum[tid] + (float)(Nx - rowK[tid]));
    __syncthreads();
    // phase 4: H-tile = P @ Whb; 8 waves x 2 sub-tiles (B fragments reused)
    int wave = tid >> 6, lane = tid & 63;
    int wr2 = wave >> 2, wc = wave & 3;
    int rowa = wr2 * 32 + (lane & 15);
    int rowb = rowa + 16;
    int kgrp = lane >> 4;
    f32x4 acca = {0.f, 0.f, 0.f, 0.f};
    f32x4 accb = {0.f, 0.f, 0.f, 0.f};
    const ushort* WB = Whb + (size_t)be * Gx * Nx;
    int g0 = wc * 16 + (lane & 15);
    const ushort* Bp = WB + (size_t)g0 * Nx + kgrp * 8;
    unsigned int aswza = ((unsigned int)(rowa & 7)) << 4;
    __builtin_amdgcn_s_setprio(1);
    #pragma unroll
    for (int ks = 0; ks < 16; ++ks) {
        bf16x8 bfv = *(const bf16x8*)(Bp + ks * 32);
        unsigned int ka = (unsigned int)(ks * 64 + kgrp * 16);
        unsigned int offa = ((unsigned int)(rowa * 1024) + ka) ^ aswza;
        unsigned int offb = ((unsigned int)(rowb * 1024) + ka) ^ aswza;
        bf16x8 afa = *(const bf16x8*)((const char*)P + offa);
        bf16x8 afb = *(const bf16x8*)((const char*)P + offb);
        acca = __builtin_amdgcn_mfma_f32_16x16x32_bf16(afa, bfv, acca, 0, 0, 0);
        accb = __builtin_amdgcn_mfma_f32_16x16x32_bf16(afb, bfv, accb, 0, 0, 0);
    }
    __builtin_amdgcn_s_setprio(0);
    #pragma unroll
    for (int reg = 0; reg < 4; ++reg) {
        int ra = n0 + wr2 * 32 + kgrp * 4 + reg;
        float iva = sinv[wr2 * 32 + kgrp * 4 + reg];
        float ivb = sinv[wr2 * 32 + 16 + kgrp * 4 + reg];
        Hb[((size_t)(b * Nx) + ra) * (Ex * Gx) + e * Gx + wc * 16 + (lane & 15)] =
            f2bf(acca[reg] * iva);
        Hb[((size_t)(b * Nx) + ra + 16) * (Ex * Gx) + e * Gx + wc * 16 + (lane & 15)] =
            f2bf(accb[reg] * ivb);
    }
}

// ---- K3: h_pre = bf16(Hb @ W0 + b) via MFMA; fp32 BN partials --------------
__global__ __launch_bounds__(256) void k3_lin0(const ushort* __restrict__ Hb,
                                               const ushort* __restrict__ W0T,
                                               const float* __restrict__ lin0_b,
                                               ushort* __restrict__ h_pre,
                                               float* __restrict__ partials) {
    __shared__ float red_s[2][256], red_q[2][256];
    int tid = threadIdx.x, wave = tid >> 6, lane = tid & 63;
    int wr = wave >> 1, wc = wave & 1;
    int row0 = blockIdx.x * 32 + wr * 16;
    int arow = lane & 15, kg = lane >> 4;
    const ushort* A = Hb + (size_t)(row0 + arow) * HIDx;
    f32x4 acc[8];
    #pragma unroll
    for (int t = 0; t < 8; ++t) acc[t] = (f32x4){0.f, 0.f, 0.f, 0.f};
    #pragma unroll
    for (int ks = 0; ks < 8; ++ks) {
        int k0 = ks * 32 + kg * 8;
        bf16x8 af = *(const bf16x8*)&A[k0];
        #pragma unroll
        for (int jt = 0; jt < 8; ++jt) {
            bf16x8 bf = *(const bf16x8*)&W0T[(size_t)(wc * 128 + jt * 16 + arow) * HIDx + k0];
            acc[jt] = __builtin_amdgcn_mfma_f32_16x16x32_bf16(af, bf, acc[jt], 0, 0, 0);
        }
    }
    #pragma unroll
    for (int jt = 0; jt < 8; ++jt) {
        int col = wc * 128 + jt * 16 + arow;
        float b = lin0_b[col];
        float s = 0.f, q = 0.f;
        #pragma unroll
        for (int reg = 0; reg < 4; ++reg) {
            float v = acc[jt][reg] + b;
            h_pre[(size_t)(row0 + kg * 4 + reg) * HIDx + col] = f2bf(v);
            s += v; q += v * v;
        }
        s += __shfl_xor(s, 16, 64); s += __shfl_xor(s, 32, 64);
        q += __shfl_xor(q, 16, 64); q += __shfl_xor(q, 32, 64);
        if (lane < 16) { red_s[wr][col] = s; red_q[wr][col] = q; }
    }
    __syncthreads();
    int j = tid;
    partials[(size_t)blockIdx.x * 2 * HIDx + j] = red_s[0][j] + red_s[1][j];
    partials[(size_t)blockIdx.x * 2 * HIDx + HIDx + j] = red_q[0][j] + red_q[1][j];
}

// ---- K3b: finalize BN stats -> scale/bias ----------------------------------
__global__ __launch_bounds__(256) void k3b_stats(const float* __restrict__ partials,
                                                 const float* __restrict__ gamma,
                                                 const float* __restrict__ beta,
                                                 float* __restrict__ sb) {
    __shared__ float rs[8][32], rq[8][32];
    int jl = threadIdx.x & 31, sl = threadIdx.x >> 5;
    int j = blockIdx.x * 32 + jl;
    float s = 0.f, q = 0.f;
    for (int blk = sl; blk < 512; blk += 8) {
        s += partials[blk * 512 + j];
        q += partials[blk * 512 + 256 + j];
    }
    rs[sl][jl] = s; rq[sl][jl] = q;
    __syncthreads();
    if (threadIdx.x < 32) {
        float S = 0.f, Q = 0.f;
        #pragma unroll
        for (int t = 0; t < 8; ++t) { S += rs[t][jl]; Q += rq[t][jl]; }
        const float invM = 1.f / 16384.f;
        float mu = S * invM;
        float var = fmaxf(Q * invM - mu * mu, 0.f);
        float sc = gamma[j] * rsqrtf(var + 1e-5f);
        sb[j] = sc;
        sb[256 + j] = beta[j] - mu * sc;
    }
}

// ---- K4: out = elu(bn(h_pre)) @ W1 + b via MFMA ----------------------------
__global__ __launch_bounds__(256) void k4_lin1(const ushort* __restrict__ h_pre,
                                               const float* __restrict__ sb,
                                               const ushort* __restrict__ W1T,
                                               const float* __restrict__ lin1_b,
                                               float* __restrict__ out) {
    int tid = threadIdx.x, wave = tid >> 6, lane = tid & 63;
    int wr = wave >> 1, wc = wave & 1;
    int row0 = blockIdx.x * 32 + wr * 16;
    int arow = lane & 15, kg = lane >> 4;
    const ushort* A = h_pre + (size_t)(row0 + arow) * HIDx;
    f32x4 acc[4];
    #pragma unroll
    for (int t = 0; t < 4; ++t) acc[t] = (f32x4){0.f, 0.f, 0.f, 0.f};
    #pragma unroll
    for (int ks = 0; ks < 8; ++ks) {
        int k0 = ks * 32 + kg * 8;
        bf16x8 hv = *(const bf16x8*)&A[k0];
        float4 sc0 = *(const float4*)&sb[k0];
        float4 sc1 = *(const float4*)&sb[k0 + 4];
        float4 bi0 = *(const float4*)&sb[256 + k0];
        float4 bi1 = *(const float4*)&sb[256 + k0 + 4];
        float scv[8] = {sc0.x, sc0.y, sc0.z, sc0.w, sc1.x, sc1.y, sc1.z, sc1.w};
        float biv[8] = {bi0.x, bi0.y, bi0.z, bi0.w, bi1.x, bi1.y, bi1.z, bi1.w};
        bf16x8 af;
        #pragma unroll
        for (int u = 0; u < 8; ++u) {
            float v = bf2f((ushort)hv[u]) * scv[u] + biv[u];
            v = v > 0.f ? v : expm1f(v);
            af[u] = (short)f2bf(v);
        }
        #pragma unroll
        for (int jt = 0; jt < 4; ++jt) {
            bf16x8 bf = *(const bf16x8*)&W1T[(size_t)(wc * 64 + jt * 16 + arow) * HIDx + k0];
            acc[jt] = __builtin_amdgcn_mfma_f32_16x16x32_bf16(af, bf, acc[jt], 0, 0, 0);
        }
    }
    #pragma unroll
    for (int jt = 0; jt < 4; ++jt) {
        int col = wc * 64 + jt * 16 + arow;
        float b = lin1_b[col];
        #pragma unroll
        for (int reg = 0; reg < 4; ++reg)
            out[(size_t)(row0 + kg * 4 + reg) * EMBx + col] = acc[jt][reg] + b;
    }
}

extern "C" void kernel_launch(void* const* d_in, const int* in_sizes, int n_in,
                              void* d_out, int out_size, void* d_ws, size_t ws_size,
                              hipStream_t stream) {
    const float* X      = (const float*)d_in[0];
    const int*   edges  = (const int*)d_in[1];
    const float* Ws     = (const float*)d_in[2];
    const float* a      = (const float*)d_in[3];
    const float* lin0_w = (const float*)d_in[4];
    const float* lin0_b = (const float*)d_in[5];
    const float* gamma  = (const float*)d_in[6];
    const float* beta   = (const float*)d_in[7];
    const float* lin1_w = (const float*)d_in[8];
    const float* lin1_b = (const float*)d_in[9];
    float* ws = (float*)d_ws;

    ushort* Whb     = (ushort*)ws;
    ushort* h_pre   = (ushort*)ws;
    ushort* binned  = (ushort*)ws + 4194304;
    int*    offs    = (int*)(ws + 2621440);
    ushort* Hb      = (ushort*)(ws + 4194304);
    float*  w1      = ws + 8388608;              // 65,536
    float*  w2      = ws + 8454144;              // 65,536
    float*  partials= ws + 8519680;              // 262,144
    float*  sb      = ws + 8781824;              // 512
    ushort* WsT     = (ushort*)(ws + 8782336);   // 32,768 ushorts
    ushort* W0T     = (ushort*)(ws + 8798720);   // 65,536 ushorts
    ushort* W1T     = (ushort*)(ws + 8831488);   // 32,768 ushorts
    float*  out     = (float*)d_out;

    k0b    <<<dim3(384), 512, 0, stream>>>(edges, lin0_w, lin1_w, Ws, W0T, W1T, WsT, binned, offs);
    k1_wh  <<<dim3(1024), 256, 0, stream>>>(X, WsT, a, Whb, w1, w2);
    k2_att <<<dim3(Bx * Ex, Nx / 64), 512, 0, stream>>>(binned, offs, Whb, w1, w2, Hb);
    k3_lin0<<<dim3(512), 256, 0, stream>>>(Hb, W0T, lin0_b, h_pre, partials);
    k3b_stats<<<8, 256, 0, stream>>>(partials, gamma, beta, sb);
    k4_lin1<<<dim3(512), 256, 0, stream>>>(h_pre, sb, W1T, lin1_b, out);
}